// Round 14
// baseline (375.862 us; speedup 1.0000x reference)
//
#include <hip/hip_runtime.h>
#include <hip/hip_bf16.h>

#define N_NODES 16000
#define N_EDGES 256000

// ---- workspace layout (4-byte units) — total 816001 * 4B = 3.26 MB (r11-validated) ----
#define OFF_SD     0          // int2  256000  (src,dst) per CSR slot, sorted by dst
#define OFF_SIMB   512000     // float 256000  raw sim -> normalized a (in place)
#define OFF_CNT    768000     // int   16000   per-dst degree
#define OFF_START  784000     // int   16001   CSR row offsets
#define OFF_CUR    800001     // int   16000   fill cursors

typedef _Float16 f16x2 __attribute__((ext_vector_type(2)));

__device__ __forceinline__ float fdot2f(f16x2 a, f16x2 b, float c) {
#if __has_builtin(__builtin_amdgcn_fdot2)
  return __builtin_amdgcn_fdot2(a, b, c, false);   // v_dot2_f32_f16, fp32 accumulate
#else
  return fmaf((float)a.x, (float)b.x, fmaf((float)a.y, (float)b.y, c));
#endif
}

__device__ __forceinline__ unsigned packh2(float a, float b) {
  union { unsigned u; f16x2 p; } v;
  v.p.x = (_Float16)a; v.p.y = (_Float16)b;
  return v.u;
}

// dot of h (8 f16 pairs) with a 16-f16 LDS column (2x ds_read_b128)
__device__ __forceinline__ float dot16h(const f16x2* hp, const unsigned* w) {
  union { uint4 u; f16x2 p[4]; } a, b;
  a.u = *(const uint4*)(w);
  b.u = *(const uint4*)(w + 4);
  float r = 0.f;
  r = fdot2f(hp[0], a.p[0], r);
  r = fdot2f(hp[1], a.p[1], r);
  r = fdot2f(hp[2], a.p[2], r);
  r = fdot2f(hp[3], a.p[3], r);
  r = fdot2f(hp[4], b.p[0], r);
  r = fdot2f(hp[5], b.p[1], r);
  r = fdot2f(hp[6], b.p[2], r);
  r = fdot2f(hp[7], b.p[3], r);
  return r;
}

__device__ __forceinline__ void load_row40(const float* __restrict__ p, float* xr) {
  const float4* rp = reinterpret_cast<const float4*>(p);
#pragma unroll
  for (int q = 0; q < 10; ++q) {
    float4 f = rp[q];
    xr[4 * q + 0] = f.x; xr[4 * q + 1] = f.y; xr[4 * q + 2] = f.z; xr[4 * q + 3] = f.w;
  }
}

__device__ __forceinline__ float xvget(const f16x2* p, int idx) {   // idx constant after unroll
  f16x2 t = p[idx >> 1];
  return (idx & 1) ? (float)t.y : (float)t.x;
}

struct Geo { float y1x, y1y, y1z, rscale, twoc, s1; };   // radial/Chebyshev seed per edge

__device__ __forceinline__ void edge_geo(const float* __restrict__ pos, int s, int d, Geo& g) {
  float vx = pos[3 * d + 0] - pos[3 * s + 0];
  float vy = pos[3 * d + 1] - pos[3 * s + 1];
  float vz = pos[3 * d + 2] - pos[3 * s + 2];
  float dist = sqrtf(fmaf(vx, vx, fmaf(vy, vy, vz * vz)));
  float dsafe = fmaxf(dist, 1e-6f);
  float rinv = 1.0f / dsafe;
  g.y1x = 1.7320508075688772f * vx * rinv;
  g.y1y = 1.7320508075688772f * vy * rinv;
  g.y1z = 1.7320508075688772f * vz * rinv;
  float sx, cx;
  sincosf(1.2566370614359172f * dsafe, &sx, &cx);
  cx = fminf(1.f, fmaxf(-1.f, cx));
  g.twoc = 2.f * cx;
  g.s1 = sx;
  g.rscale = (dist < 2.5f) ? (5.059644256269407f * rinv) : 0.f;   // sqrt(2/2.5)*sqrt(32)
}

// h for TWO edges with one pass over W1 (shared ds_reads). W1 packed [bp*16+t].
__device__ __forceinline__ void edge_h2(const Geo& gA, const Geo& gB, const unsigned* W1,
                                        f16x2* hpA, f16x2* hpB) {
  float preA[16], preB[16];
#pragma unroll
  for (int t = 0; t < 16; ++t) { preA[t] = 0.f; preB[t] = 0.f; }
  float spA = 0.f, scA = gA.s1, spB = 0.f, scB = gB.s1;
#pragma unroll
  for (int bp = 0; bp < 16; ++bp) {
    float a0 = gA.rscale * scA; float sn = fmaf(gA.twoc, scA, -spA); spA = scA; scA = sn;
    float a1 = gA.rscale * scA; sn = fmaf(gA.twoc, scA, -spA); spA = scA; scA = sn;
    float b0 = gB.rscale * scB; sn = fmaf(gB.twoc, scB, -spB); spB = scB; scB = sn;
    float b1 = gB.rscale * scB; sn = fmaf(gB.twoc, scB, -spB); spB = scB; scB = sn;
    union { unsigned u; f16x2 p; } ra, rb;
    ra.u = packh2(a0, a1); rb.u = packh2(b0, b1);
    union { uint4 u[4]; f16x2 p[16]; } w;
    w.u[0] = *(const uint4*)(W1 + bp * 16);
    w.u[1] = *(const uint4*)(W1 + bp * 16 + 4);
    w.u[2] = *(const uint4*)(W1 + bp * 16 + 8);
    w.u[3] = *(const uint4*)(W1 + bp * 16 + 12);
#pragma unroll
    for (int t = 0; t < 16; ++t) {
      preA[t] = fdot2f(ra.p, w.p[t], preA[t]);
      preB[t] = fdot2f(rb.p, w.p[t], preB[t]);
    }
  }
#pragma unroll
  for (int tp = 0; tp < 8; ++tp) {
    float a0 = preA[2 * tp]     / (1.f + __expf(-preA[2 * tp]));
    float a1 = preA[2 * tp + 1] / (1.f + __expf(-preA[2 * tp + 1]));
    float b0 = preB[2 * tp]     / (1.f + __expf(-preB[2 * tp]));
    float b1 = preB[2 * tp + 1] / (1.f + __expf(-preB[2 * tp + 1]));
    hpA[tp].x = (_Float16)a0; hpA[tp].y = (_Float16)a1;
    hpB[tp].x = (_Float16)b0; hpB[tp].y = (_Float16)b1;
  }
}

// ================= CSR build =================
__global__ void k_hist(const int* __restrict__ edst, int* __restrict__ cnt) {
  int e = blockIdx.x * 256 + threadIdx.x;
  atomicAdd(&cnt[edst[e]], 1);
}

__global__ void __launch_bounds__(1024) k_scan(const int* __restrict__ cnt,
                                               int* __restrict__ start, int* __restrict__ cur) {
  __shared__ int part[1024];
  int t = threadIdx.x;
  int base = t * 16;
  int local[16];
  int sum = 0;
#pragma unroll
  for (int i = 0; i < 16; ++i) {
    int idx = base + i;
    int c = (idx < N_NODES) ? cnt[idx] : 0;
    local[i] = sum; sum += c;
  }
  part[t] = sum;
  __syncthreads();
  for (int off = 1; off < 1024; off <<= 1) {
    int v = (t >= off) ? part[t - off] : 0;
    __syncthreads();
    part[t] += v;
    __syncthreads();
  }
  int prev = (t == 0) ? 0 : part[t - 1];
#pragma unroll
  for (int i = 0; i < 16; ++i) {
    int idx = base + i;
    if (idx < N_NODES) { int st = prev + local[i]; start[idx] = st; cur[idx] = st; }
  }
  if (t == 0) start[N_NODES] = N_EDGES;
}

__global__ void k_fill(const int* __restrict__ esrc, const int* __restrict__ edst,
                       int* __restrict__ cur, int2* __restrict__ sd) {
  int e = blockIdx.x * 256 + threadIdx.x;
  int d = edst[e];
  int slot = atomicAdd(&cur[d], 1);
  sd[slot] = make_int2(esrc[e], d);
}

// ================= pass 1: 2 edges/lane, f16 weights, sim folded on the fly =================
// Lw (uint): [0,256) W1K packed | [256,2560) W2K^T packed [col*8+tp], scaled 1/sqrt16/sqrt24
// Ls (float): [0,128) WQS*0.25 | [128,160) WQV/sqrt8 | [160,224) WSS/sqrt80 | [224,240) WVV/(sqrt80*sqrt3)
__global__ void __launch_bounds__(256) k_edge1(
    const float* __restrict__ pos, const float* __restrict__ x,
    const float* __restrict__ Wq_s, const float* __restrict__ Wq_v,
    const float* __restrict__ Wk1, const float* __restrict__ Wk2,
    const float* __restrict__ Wss, const float* __restrict__ Wvv,
    const int2* __restrict__ sd, float* __restrict__ simb) {
  __shared__ __align__(16) unsigned Lw[2560];
  __shared__ float Ls[240];
  for (int i = threadIdx.x; i < 2560; i += 256) {
    unsigned v;
    if (i < 256) {
      int bp = i >> 4, t = i & 15;
      v = packh2(Wk1[(2 * bp) * 16 + t] * 0.17677669529663687f,
                 Wk1[(2 * bp + 1) * 16 + t] * 0.17677669529663687f);
    } else {
      int j = i - 256; int col = j >> 3, tp = j & 7;
      v = packh2(Wk2[(2 * tp) * 288 + col] * 0.051031036307982884f,
                 Wk2[(2 * tp + 1) * 288 + col] * 0.051031036307982884f);
    }
    Lw[i] = v;
  }
  for (int i = threadIdx.x; i < 240; i += 256) {
    float v;
    if (i < 128)      v = Wq_s[i] * 0.25f;
    else if (i < 160) v = Wq_v[i - 128] * 0.3535533905932738f;
    else if (i < 224) v = Wss[i - 160] * 0.11180339887498948f;
    else              v = Wvv[i - 224] * 0.06454972243679028f;
    Ls[i] = v;
  }
  __syncthreads();

  int wave = threadIdx.x >> 6, lane = threadIdx.x & 63;
  int base = blockIdx.x * 512 + wave * 128;      // 500 blocks * 512 slots
  int jA = base + lane, jB = base + 64 + lane;
  int2 eA = sd[jA], eB = sd[jB];

  // q-tilde (q contracted with Wss/Wvv) per edge; xd registers released after
  float qsA[8], qvA[12], qsB[8], qvB[12];
#pragma unroll
  for (int pass = 0; pass < 2; ++pass) {
    int d = pass ? eB.y : eA.y;
    float* qs = pass ? qsB : qsA;
    float* qv = pass ? qvB : qvA;
    float xd[40];
    load_row40(x + 40 * d, xd);
    float qd[8], qvd[12];
#pragma unroll
    for (int o = 0; o < 8; ++o) qd[o] = 0.f;
#pragma unroll
    for (int i = 0; i < 16; ++i)
#pragma unroll
      for (int o = 0; o < 8; ++o) qd[o] = fmaf(xd[i], Ls[8 * i + o], qd[o]);
#pragma unroll
    for (int k = 0; k < 12; ++k) qvd[k] = 0.f;
#pragma unroll
    for (int i = 0; i < 8; ++i)
#pragma unroll
      for (int o = 0; o < 4; ++o)
#pragma unroll
        for (int c = 0; c < 3; ++c)
          qvd[3 * o + c] = fmaf(xd[16 + 3 * i + c], Ls[128 + 4 * i + o], qvd[3 * o + c]);
#pragma unroll
    for (int j = 0; j < 8; ++j) {
      float t = 0.f;
#pragma unroll
      for (int i = 0; i < 8; ++i) t = fmaf(qd[i], Ls[160 + 8 * i + j], t);
      qs[j] = t;
    }
#pragma unroll
    for (int j = 0; j < 4; ++j)
#pragma unroll
      for (int c = 0; c < 3; ++c) {
        float t = 0.f;
#pragma unroll
        for (int i = 0; i < 4; ++i) t = fmaf(qvd[3 * i + c], Ls[224 + 4 * i + j], t);
        qv[3 * j + c] = t;
      }
  }

  Geo gA, gB;
  edge_geo(pos, eA.x, eA.y, gA);
  edge_geo(pos, eB.x, eB.y, gB);
  f16x2 hpA[8], hpB[8];
  edge_h2(gA, gB, Lw, hpA, hpB);

  // src features: xs fp32, xv packed f16, B fp32
  float xsA[16], xsB[16], BA[8], BB[8];
  f16x2 xvA[12], xvB[12];
#pragma unroll
  for (int pass = 0; pass < 2; ++pass) {
    int s = pass ? eB.x : eA.x;
    const Geo& g = pass ? gB : gA;
    float* xs = pass ? xsB : xsA;
    float* B  = pass ? BB  : BA;
    f16x2* xv = pass ? xvB : xvA;
    float xr[40];
    load_row40(x + 40 * s, xr);
#pragma unroll
    for (int i = 0; i < 16; ++i) xs[i] = xr[i];
#pragma unroll
    for (int i = 0; i < 8; ++i)
      B[i] = 0.5773502691896258f *
             fmaf(xr[16 + 3 * i], g.y1x, fmaf(xr[17 + 3 * i], g.y1y, xr[18 + 3 * i] * g.y1z));
#pragma unroll
    for (int k = 0; k < 12; ++k) {
      xv[k].x = (_Float16)xr[16 + 2 * k];
      xv[k].y = (_Float16)xr[17 + 2 * k];
    }
  }

  const unsigned* W2 = Lw + 256;
  float simA = 0.f, simB = 0.f;
#pragma unroll
  for (int o = 0; o < 8; ++o) {      // ks columns
    float accA = 0.f, accB = 0.f;
#pragma unroll
    for (int i = 0; i < 16; ++i) {
      const unsigned* w = W2 + ((i * 8 + o) << 3);
      accA = fmaf(xsA[i], dot16h(hpA, w), accA);
      accB = fmaf(xsB[i], dot16h(hpB, w), accB);
    }
#pragma unroll
    for (int i = 0; i < 8; ++i) {
      const unsigned* w = W2 + ((128 + i * 8 + o) << 3);
      accA = fmaf(BA[i], dot16h(hpA, w), accA);
      accB = fmaf(BB[i], dot16h(hpB, w), accB);
    }
    simA = fmaf(qsA[o], accA, simA);
    simB = fmaf(qsB[o], accB, simB);
  }
#pragma unroll
  for (int o = 0; o < 4; ++o) {      // kv columns
    float s1A = 0.f, s1B = 0.f;
#pragma unroll
    for (int i = 0; i < 16; ++i) {
      const unsigned* w = W2 + ((192 + i * 4 + o) << 3);
      s1A = fmaf(xsA[i], dot16h(hpA, w), s1A);
      s1B = fmaf(xsB[i], dot16h(hpB, w), s1B);
    }
    float s2Ax = 0.f, s2Ay = 0.f, s2Az = 0.f, s2Bx = 0.f, s2By = 0.f, s2Bz = 0.f;
#pragma unroll
    for (int i = 0; i < 8; ++i) {
      const unsigned* w = W2 + ((256 + i * 4 + o) << 3);
      float wwA = dot16h(hpA, w), wwB = dot16h(hpB, w);
      s2Ax = fmaf(xvget(xvA, 3 * i),     wwA, s2Ax);
      s2Ay = fmaf(xvget(xvA, 3 * i + 1), wwA, s2Ay);
      s2Az = fmaf(xvget(xvA, 3 * i + 2), wwA, s2Az);
      s2Bx = fmaf(xvget(xvB, 3 * i),     wwB, s2Bx);
      s2By = fmaf(xvget(xvB, 3 * i + 1), wwB, s2By);
      s2Bz = fmaf(xvget(xvB, 3 * i + 2), wwB, s2Bz);
    }
    simA = fmaf(qvA[3 * o],     fmaf(gA.y1x, s1A, s2Ax), simA);
    simA = fmaf(qvA[3 * o + 1], fmaf(gA.y1y, s1A, s2Ay), simA);
    simA = fmaf(qvA[3 * o + 2], fmaf(gA.y1z, s1A, s2Az), simA);
    simB = fmaf(qvB[3 * o],     fmaf(gB.y1x, s1B, s2Bx), simB);
    simB = fmaf(qvB[3 * o + 1], fmaf(gB.y1y, s1B, s2By), simB);
    simB = fmaf(qvB[3 * o + 2], fmaf(gB.y1z, s1B, s2Bz), simB);
  }
  simb[jA] = simA;
  simb[jB] = simB;
}

// ================= exact per-dst softmax: simb <- exp(sim - max)/Z =================
__global__ void k_norm(const int* __restrict__ start, float* __restrict__ simb) {
  int n = blockIdx.x * 256 + threadIdx.x;
  if (n >= N_NODES) return;
  int a = start[n], b = start[n + 1];
  if (a == b) return;
  float m = -3.4e38f;
  for (int j = a; j < b; ++j) m = fmaxf(m, simb[j]);
  float Z = 0.f;
  for (int j = a; j < b; ++j) { float t = __expf(simb[j] - m); simb[j] = t; Z += t; }
  float inv = 1.f / Z;
  for (int j = a; j < b; ++j) simb[j] *= inv;
}

// ================= pass 2: 2 edges/lane, f16 weights, segmented scatter =================
// Lw (uint): [0,256) W1V packed | [256,4864) W2V^T packed [col*8+tp], scaled
__global__ void __launch_bounds__(256) k_edge2(
    const float* __restrict__ pos, const float* __restrict__ x,
    const float* __restrict__ Wv1, const float* __restrict__ Wv2,
    const int2* __restrict__ sd, const float* __restrict__ ab, float* __restrict__ out) {
  __shared__ __align__(16) unsigned Lw[4864];
  for (int i = threadIdx.x; i < 4864; i += 256) {
    unsigned v;
    if (i < 256) {
      int bp = i >> 4, t = i & 15;
      v = packh2(Wv1[(2 * bp) * 16 + t] * 0.17677669529663687f,
                 Wv1[(2 * bp + 1) * 16 + t] * 0.17677669529663687f);
    } else {
      int j = i - 256; int col = j >> 3, tp = j & 7;
      v = packh2(Wv2[(2 * tp) * 576 + col] * 0.051031036307982884f,
                 Wv2[(2 * tp + 1) * 576 + col] * 0.051031036307982884f);
    }
    Lw[i] = v;
  }
  __syncthreads();

  int wave = threadIdx.x >> 6, lane = threadIdx.x & 63;
  int base = blockIdx.x * 512 + wave * 128;
  int jA = base + lane, jB = base + 64 + lane;
  int2 eA = sd[jA], eB = sd[jB];
  int dA = eA.y, dB = eB.y;

  bool sameA[6], sameB[6];
#pragma unroll
  for (int k = 0; k < 6; ++k) {
    int da = __shfl_down(dA, 1 << k, 64);
    int db = __shfl_down(dB, 1 << k, 64);
    bool in = (lane + (1 << k)) < 64;
    sameA[k] = in && (da == dA);
    sameB[k] = in && (db == dB);
  }
  int dpA = __shfl_up(dA, 1, 64), dpB = __shfl_up(dB, 1, 64);
  bool headA = (lane == 0) || (dpA != dA);
  bool headB = (lane == 0) || (dpB != dB);

  Geo gA, gB;
  edge_geo(pos, eA.x, dA, gA);
  edge_geo(pos, eB.x, dB, gB);
  f16x2 hpA[8], hpB[8];
  edge_h2(gA, gB, Lw, hpA, hpB);

  float xsA[16], xsB[16], BA[8], BB[8];
  f16x2 xvA[12], xvB[12];
#pragma unroll
  for (int pass = 0; pass < 2; ++pass) {
    int s = pass ? eB.x : eA.x;
    const Geo& g = pass ? gB : gA;
    float* xs = pass ? xsB : xsA;
    float* B  = pass ? BB  : BA;
    f16x2* xv = pass ? xvB : xvA;
    float xr[40];
    load_row40(x + 40 * s, xr);
#pragma unroll
    for (int i = 0; i < 16; ++i) xs[i] = xr[i];
#pragma unroll
    for (int i = 0; i < 8; ++i)
      B[i] = 0.5773502691896258f *
             fmaf(xr[16 + 3 * i], g.y1x, fmaf(xr[17 + 3 * i], g.y1y, xr[18 + 3 * i] * g.y1z));
#pragma unroll
    for (int k = 0; k < 12; ++k) {
      xv[k].x = (_Float16)xr[16 + 2 * k];
      xv[k].y = (_Float16)xr[17 + 2 * k];
    }
  }

  float aA = ab[jA], aB = ab[jB];
  const unsigned* W2 = Lw + 256;
  float* opA = out + 40 * dA;
  float* opB = out + 40 * dB;

#pragma unroll
  for (int o = 0; o < 16; ++o) {     // scalar outputs
    float accA = 0.f, accB = 0.f;
#pragma unroll
    for (int i = 0; i < 16; ++i) {
      const unsigned* w = W2 + ((i * 16 + o) << 3);
      accA = fmaf(xsA[i], dot16h(hpA, w), accA);
      accB = fmaf(xsB[i], dot16h(hpB, w), accB);
    }
#pragma unroll
    for (int i = 0; i < 8; ++i) {
      const unsigned* w = W2 + ((256 + i * 16 + o) << 3);
      accA = fmaf(BA[i], dot16h(hpA, w), accA);
      accB = fmaf(BB[i], dot16h(hpB, w), accB);
    }
    float vA = aA * accA;
#pragma unroll
    for (int k = 0; k < 6; ++k) {
      float ov = __shfl_down(vA, 1 << k, 64);
      vA += sameA[k] ? ov : 0.f;
    }
    if (headA) atomicAdd(opA + o, vA);
    float vB = aB * accB;
#pragma unroll
    for (int k = 0; k < 6; ++k) {
      float ov = __shfl_down(vB, 1 << k, 64);
      vB += sameB[k] ? ov : 0.f;
    }
    if (headB) atomicAdd(opB + o, vB);
  }
#pragma unroll
  for (int o = 0; o < 8; ++o) {      // vector outputs
    float s1A = 0.f, s1B = 0.f;
#pragma unroll
    for (int i = 0; i < 16; ++i) {
      const unsigned* w = W2 + ((384 + i * 8 + o) << 3);
      s1A = fmaf(xsA[i], dot16h(hpA, w), s1A);
      s1B = fmaf(xsB[i], dot16h(hpB, w), s1B);
    }
    float s2Ax = 0.f, s2Ay = 0.f, s2Az = 0.f, s2Bx = 0.f, s2By = 0.f, s2Bz = 0.f;
#pragma unroll
    for (int i = 0; i < 8; ++i) {
      const unsigned* w = W2 + ((512 + i * 8 + o) << 3);
      float wwA = dot16h(hpA, w), wwB = dot16h(hpB, w);
      s2Ax = fmaf(xvget(xvA, 3 * i),     wwA, s2Ax);
      s2Ay = fmaf(xvget(xvA, 3 * i + 1), wwA, s2Ay);
      s2Az = fmaf(xvget(xvA, 3 * i + 2), wwA, s2Az);
      s2Bx = fmaf(xvget(xvB, 3 * i),     wwB, s2Bx);
      s2By = fmaf(xvget(xvB, 3 * i + 1), wwB, s2By);
      s2Bz = fmaf(xvget(xvB, 3 * i + 2), wwB, s2Bz);
    }
    float vcA[3], vcB[3];
    vcA[0] = aA * fmaf(gA.y1x, s1A, s2Ax);
    vcA[1] = aA * fmaf(gA.y1y, s1A, s2Ay);
    vcA[2] = aA * fmaf(gA.y1z, s1A, s2Az);
    vcB[0] = aB * fmaf(gB.y1x, s1B, s2Bx);
    vcB[1] = aB * fmaf(gB.y1y, s1B, s2By);
    vcB[2] = aB * fmaf(gB.y1z, s1B, s2Bz);
#pragma unroll
    for (int c = 0; c < 3; ++c) {
      float vA = vcA[c];
#pragma unroll
      for (int k = 0; k < 6; ++k) {
        float ov = __shfl_down(vA, 1 << k, 64);
        vA += sameA[k] ? ov : 0.f;
      }
      if (headA) atomicAdd(opA + 16 + 3 * o + c, vA);
      float vB = vcB[c];
#pragma unroll
      for (int k = 0; k < 6; ++k) {
        float ov = __shfl_down(vB, 1 << k, 64);
        vB += sameB[k] ? ov : 0.f;
      }
      if (headB) atomicAdd(opB + 16 + 3 * o + c, vB);
    }
  }
}

extern "C" void kernel_launch(void* const* d_in, const int* in_sizes, int n_in,
                              void* d_out, int out_size, void* d_ws, size_t ws_size,
                              hipStream_t stream) {
  (void)in_sizes; (void)n_in; (void)out_size; (void)ws_size;
  const float* pos  = (const float*)d_in[0];
  const float* x    = (const float*)d_in[1];
  const float* Wq_s = (const float*)d_in[2];
  const float* Wq_v = (const float*)d_in[3];
  const float* Wk1  = (const float*)d_in[4];
  const float* Wk2  = (const float*)d_in[5];
  const float* Wv1  = (const float*)d_in[6];
  const float* Wv2  = (const float*)d_in[7];
  const float* Wss  = (const float*)d_in[8];
  const float* Wvv  = (const float*)d_in[9];
  const int* esrc = (const int*)d_in[10];
  const int* edst = (const int*)d_in[11];
  int*   wsi  = (int*)d_ws;
  float* wsf  = (float*)d_ws;
  float* out  = (float*)d_out;

  int2*  sd    = (int2*)(wsi + OFF_SD);
  float* simb  = wsf + OFF_SIMB;
  int*   cnt   = wsi + OFF_CNT;
  int*   start = wsi + OFF_START;
  int*   cur   = wsi + OFF_CUR;

  hipMemsetAsync(cnt, 0, (size_t)N_NODES * sizeof(int), stream);
  hipMemsetAsync(out, 0, (size_t)(N_NODES * 40) * sizeof(float), stream);
  k_hist<<<1000, 256, 0, stream>>>(edst, cnt);
  k_scan<<<1, 1024, 0, stream>>>(cnt, start, cur);
  k_fill<<<1000, 256, 0, stream>>>(esrc, edst, cur, sd);
  k_edge1<<<500, 256, 0, stream>>>(pos, x, Wq_s, Wq_v, Wk1, Wk2, Wss, Wvv, sd, simb);
  k_norm<<<63, 256, 0, stream>>>(start, simb);
  k_edge2<<<500, 256, 0, stream>>>(pos, x, Wv1, Wv2, sd, simb, out);
}

// Round 15
// 276.766 us; speedup vs baseline: 1.3580x; 1.3580x over previous
//
#include <hip/hip_runtime.h>
#include <hip/hip_bf16.h>

#define N_NODES 16000
#define N_EDGES 256000

// ---- workspace layout (4-byte units) — total 816001 * 4B = 3.26 MB (r11-validated) ----
#define OFF_SD     0          // int2  256000  (src,dst) per CSR slot, sorted by dst
#define OFF_SIMB   512000     // float 256000  raw sim -> normalized a (in place)
#define OFF_CNT    768000     // int   16000   per-dst degree
#define OFF_START  784000     // int   16001   CSR row offsets
#define OFF_CUR    800001     // int   16000   fill cursors

typedef _Float16 f16x2 __attribute__((ext_vector_type(2)));
typedef _Float16 f16x8v __attribute__((ext_vector_type(8)));
typedef float f32x4v __attribute__((ext_vector_type(4)));

__device__ __forceinline__ float fdot2f(f16x2 a, f16x2 b, float c) {
#if __has_builtin(__builtin_amdgcn_fdot2)
  return __builtin_amdgcn_fdot2(a, b, c, false);   // v_dot2_f32_f16, fp32 accumulate
#else
  return fmaf((float)a.x, (float)b.x, fmaf((float)a.y, (float)b.y, c));
#endif
}

__device__ __forceinline__ unsigned packh2(float a, float b) {
  union { unsigned u; f16x2 p; } v;
  v.p.x = (_Float16)a; v.p.y = (_Float16)b;
  return v.u;
}

// dot of h (8 packed f16 pairs) with a 16-f16 LDS column (2x ds_read_b128) — used by k_edge1
__device__ __forceinline__ float dot16h(const f16x2* hp, const unsigned* w) {
  union { uint4 u; f16x2 p[4]; } a, b;
  a.u = *(const uint4*)(w);
  b.u = *(const uint4*)(w + 4);
  float r = 0.f;
  r = fdot2f(hp[0], a.p[0], r);
  r = fdot2f(hp[1], a.p[1], r);
  r = fdot2f(hp[2], a.p[2], r);
  r = fdot2f(hp[3], a.p[3], r);
  r = fdot2f(hp[4], b.p[0], r);
  r = fdot2f(hp[5], b.p[1], r);
  r = fdot2f(hp[6], b.p[2], r);
  r = fdot2f(hp[7], b.p[3], r);
  return r;
}

// load a 40-float row (rows are 160B = 16B-aligned) via 10 x float4
__device__ __forceinline__ void load_row40(const float* __restrict__ p, float* xr) {
  const float4* rp = reinterpret_cast<const float4*>(p);
#pragma unroll
  for (int q = 0; q < 10; ++q) {
    float4 f = rp[q];
    xr[4 * q + 0] = f.x; xr[4 * q + 1] = f.y; xr[4 * q + 2] = f.z; xr[4 * q + 3] = f.w;
  }
}

struct EdgeGeom { float vhx, vhy, vhz, y1x, y1y, y1z; };

// geometry + radial basis + h = silu(rad @ W1n), packed as 8 f16 pairs.
// W1 (LDS, packed): [bp*16 + t] = half2(W1[2bp][t], W1[2bp+1][t]) * 1/sqrt(32)
__device__ __forceinline__ void edge_h_pk(const float* __restrict__ pos, int s, int d,
                                          const unsigned* W1, f16x2* hp, EdgeGeom& g) {
  float vx = pos[3 * d + 0] - pos[3 * s + 0];
  float vy = pos[3 * d + 1] - pos[3 * s + 1];
  float vz = pos[3 * d + 2] - pos[3 * s + 2];
  float dist = sqrtf(fmaf(vx, vx, fmaf(vy, vy, vz * vz)));
  float dsafe = fmaxf(dist, 1e-6f);
  float rinv = 1.0f / dsafe;
  g.vhx = vx * rinv; g.vhy = vy * rinv; g.vhz = vz * rinv;
  g.y1x = 1.7320508075688772f * g.vhx;
  g.y1y = 1.7320508075688772f * g.vhy;
  g.y1z = 1.7320508075688772f * g.vhz;
  float pre[16];
#pragma unroll
  for (int t = 0; t < 16; ++t) pre[t] = 0.f;
  float sx, cx;
  sincosf(1.2566370614359172f * dsafe, &sx, &cx);   // pi/R_CUT * dsafe
  cx = fminf(1.f, fmaxf(-1.f, cx));
  float twoc = 2.f * cx;
  float sprev = 0.f, scur = sx;
  float rscale = (dist < 2.5f) ? (5.059644256269407f * rinv) : 0.f;  // sqrt(2/2.5)*sqrt(32)
#pragma unroll
  for (int bp = 0; bp < 16; ++bp) {
    float r0 = rscale * scur;
    float sn = fmaf(twoc, scur, -sprev); sprev = scur; scur = sn;
    float r1 = rscale * scur;
    sn = fmaf(twoc, scur, -sprev); sprev = scur; scur = sn;
    union { unsigned u; f16x2 p; } rp; rp.p.x = (_Float16)r0; rp.p.y = (_Float16)r1;
    union { uint4 u[4]; f16x2 p[16]; } w;
    w.u[0] = *(const uint4*)(W1 + bp * 16);
    w.u[1] = *(const uint4*)(W1 + bp * 16 + 4);
    w.u[2] = *(const uint4*)(W1 + bp * 16 + 8);
    w.u[3] = *(const uint4*)(W1 + bp * 16 + 12);
#pragma unroll
    for (int t = 0; t < 16; ++t) pre[t] = fdot2f(rp.p, w.p[t], pre[t]);
  }
#pragma unroll
  for (int tp = 0; tp < 8; ++tp) {
    float h0 = pre[2 * tp]     / (1.f + __expf(-pre[2 * tp]));      // silu (fp32)
    float h1 = pre[2 * tp + 1] / (1.f + __expf(-pre[2 * tp + 1]));
    hp[tp].x = (_Float16)h0; hp[tp].y = (_Float16)h1;
  }
}

// ================= CSR build =================
__global__ void k_hist(const int* __restrict__ edst, int* __restrict__ cnt) {
  int e = blockIdx.x * 256 + threadIdx.x;
  atomicAdd(&cnt[edst[e]], 1);
}

__global__ void __launch_bounds__(1024) k_scan(const int* __restrict__ cnt,
                                               int* __restrict__ start, int* __restrict__ cur) {
  __shared__ int part[1024];
  int t = threadIdx.x;
  int base = t * 16;
  int local[16];
  int sum = 0;
#pragma unroll
  for (int i = 0; i < 16; ++i) {
    int idx = base + i;
    int c = (idx < N_NODES) ? cnt[idx] : 0;
    local[i] = sum; sum += c;
  }
  part[t] = sum;
  __syncthreads();
  for (int off = 1; off < 1024; off <<= 1) {
    int v = (t >= off) ? part[t - off] : 0;
    __syncthreads();
    part[t] += v;
    __syncthreads();
  }
  int prev = (t == 0) ? 0 : part[t - 1];
#pragma unroll
  for (int i = 0; i < 16; ++i) {
    int idx = base + i;
    if (idx < N_NODES) { int st = prev + local[i]; start[idx] = st; cur[idx] = st; }
  }
  if (t == 0) start[N_NODES] = N_EDGES;
}

__global__ void k_fill(const int* __restrict__ esrc, const int* __restrict__ edst,
                       int* __restrict__ cur, int2* __restrict__ sd) {
  int e = blockIdx.x * 256 + threadIdx.x;
  int d = edst[e];
  int slot = atomicAdd(&cur[d], 1);
  sd[slot] = make_int2(esrc[e], d);
}

// ================= pass 1 (r11-exact): q + k TP (f16 weights) + raw sim =================
__global__ void __launch_bounds__(256) k_edge1(
    const float* __restrict__ pos, const float* __restrict__ x,
    const float* __restrict__ Wq_s, const float* __restrict__ Wq_v,
    const float* __restrict__ Wk1, const float* __restrict__ Wk2,
    const float* __restrict__ Wss, const float* __restrict__ Wvv,
    const int2* __restrict__ sd, float* __restrict__ simb) {
  __shared__ __align__(16) unsigned Lw[2560];
  __shared__ float Ls[240];
  for (int i = threadIdx.x; i < 2560; i += 256) {
    unsigned v;
    if (i < 256) {
      int bp = i >> 4, t = i & 15;
      v = packh2(Wk1[(2 * bp) * 16 + t] * 0.17677669529663687f,
                 Wk1[(2 * bp + 1) * 16 + t] * 0.17677669529663687f);
    } else {
      int j = i - 256; int col = j >> 3, tp = j & 7;
      v = packh2(Wk2[(2 * tp) * 288 + col] * 0.051031036307982884f,
                 Wk2[(2 * tp + 1) * 288 + col] * 0.051031036307982884f);
    }
    Lw[i] = v;
  }
  for (int i = threadIdx.x; i < 240; i += 256) {
    float v;
    if (i < 128)      v = Wq_s[i] * 0.25f;
    else if (i < 160) v = Wq_v[i - 128] * 0.3535533905932738f;
    else if (i < 224) v = Wss[i - 160] * 0.11180339887498948f;
    else              v = Wvv[i - 224] * 0.06454972243679028f;
    Ls[i] = v;
  }
  __syncthreads();

  int slot = blockIdx.x * 256 + threadIdx.x;
  int2 e = sd[slot];
  int s = e.x, d = e.y;
  f16x2 hp[8]; EdgeGeom g;
  edge_h_pk(pos, s, d, Lw, hp, g);

  float qd[8], qvd[12];
  {
    float xd[40];
    load_row40(x + 40 * d, xd);
#pragma unroll
    for (int o = 0; o < 8; ++o) qd[o] = 0.f;
#pragma unroll
    for (int i = 0; i < 16; ++i)
#pragma unroll
      for (int o = 0; o < 8; ++o) qd[o] = fmaf(xd[i], Ls[8 * i + o], qd[o]);
#pragma unroll
    for (int k = 0; k < 12; ++k) qvd[k] = 0.f;
#pragma unroll
    for (int i = 0; i < 8; ++i)
#pragma unroll
      for (int o = 0; o < 4; ++o)
#pragma unroll
        for (int c = 0; c < 3; ++c)
          qvd[3 * o + c] = fmaf(xd[16 + 3 * i + c], Ls[128 + 4 * i + o], qvd[3 * o + c]);
  }

  float xr[40];
  load_row40(x + 40 * s, xr);
  const float* xs = xr;
  const float* xv = xr + 16;
  float B[8];
#pragma unroll
  for (int i = 0; i < 8; ++i)
    B[i] = fmaf(xv[3 * i], g.vhx, fmaf(xv[3 * i + 1], g.vhy, xv[3 * i + 2] * g.vhz));

  const unsigned* W2 = Lw + 256;
  float ks[8];
#pragma unroll
  for (int o = 0; o < 8; ++o) {
    float acc = 0.f;
#pragma unroll
    for (int i = 0; i < 16; ++i) acc = fmaf(xs[i], dot16h(hp, W2 + ((i * 8 + o) << 3)), acc);
#pragma unroll
    for (int i = 0; i < 8; ++i)  acc = fmaf(B[i], dot16h(hp, W2 + ((128 + i * 8 + o) << 3)), acc);
    ks[o] = acc;
  }
  float kv[12];
#pragma unroll
  for (int o = 0; o < 4; ++o) {
    float s1 = 0.f;
#pragma unroll
    for (int i = 0; i < 16; ++i) s1 = fmaf(xs[i], dot16h(hp, W2 + ((192 + i * 4 + o) << 3)), s1);
    float s2x = 0.f, s2y = 0.f, s2z = 0.f;
#pragma unroll
    for (int i = 0; i < 8; ++i) {
      float w = dot16h(hp, W2 + ((256 + i * 4 + o) << 3));
      s2x = fmaf(xv[3 * i], w, s2x);
      s2y = fmaf(xv[3 * i + 1], w, s2y);
      s2z = fmaf(xv[3 * i + 2], w, s2z);
    }
    kv[3 * o]     = fmaf(g.y1x, s1, s2x);
    kv[3 * o + 1] = fmaf(g.y1y, s1, s2y);
    kv[3 * o + 2] = fmaf(g.y1z, s1, s2z);
  }

  float sim = 0.f;
#pragma unroll
  for (int jj = 0; jj < 8; ++jj) {
    float t = 0.f;
#pragma unroll
    for (int i = 0; i < 8; ++i) t = fmaf(qd[i], Ls[160 + 8 * i + jj], t);
    sim = fmaf(t, ks[jj], sim);
  }
#pragma unroll
  for (int jj = 0; jj < 4; ++jj)
#pragma unroll
    for (int c = 0; c < 3; ++c) {
      float t = 0.f;
#pragma unroll
      for (int i = 0; i < 4; ++i) t = fmaf(qvd[3 * i + c], Ls[224 + 4 * i + jj], t);
      sim = fmaf(t, kv[3 * jj + c], sim);
    }
  simb[slot] = sim;
}

// ================= exact per-dst softmax =================
__global__ void k_norm(const int* __restrict__ start, float* __restrict__ simb) {
  int n = blockIdx.x * 256 + threadIdx.x;
  if (n >= N_NODES) return;
  int a = start[n], b = start[n + 1];
  if (a == b) return;
  float m = -3.4e38f;
  for (int j = a; j < b; ++j) m = fmaxf(m, simb[j]);
  float Z = 0.f;
  for (int j = a; j < b; ++j) { float t = __expf(simb[j] - m); simb[j] = t; Z += t; }
  float inv = 1.f / Z;
  for (int j = a; j < b; ++j) simb[j] *= inv;
}

// ================= pass 2: MFMA — P[64][576] = H[64][16] x W2V[16][576] per wave ============
// A-frag (HW-verified m120): lane(q,m) holds A[m][k=8q+j]; K padded 16->32 (quads 2,3 zero).
// B-frag (duality):          lane(q,m) holds B[k=8q+j][n=m].
// C/D (HW-verified m89):     lane(q,m) holds D[row=4q+r][col=m]  (row=edge, col=W2 col).
#define PTR 72   // padded row stride of the per-wave P buffer (col-major), conflict-free
__global__ void __launch_bounds__(256) k_edge2(
    const float* __restrict__ pos, const float* __restrict__ x,
    const float* __restrict__ Wv1, const float* __restrict__ Wv2,
    const int2* __restrict__ sd, const float* __restrict__ ab, float* __restrict__ out) {
  __shared__ __align__(16) unsigned LW1[256];        // W1V packed (r11 layout)
  __shared__ __align__(16) uint4 BF[36 * 32];        // B-frags, quads 0..1 only (18 KB)
  __shared__ __align__(16) unsigned HT[4][64][8];    // per-wave h rows, 16 f16 each (8 KB)
  __shared__ __align__(16) float PT[4][16][PTR];     // per-wave P, col-major padded (18 KB)

  for (int i = threadIdx.x; i < 256; i += 256) {
    int bp = i >> 4, t = i & 15;
    LW1[i] = packh2(Wv1[(2 * bp) * 16 + t] * 0.17677669529663687f,
                    Wv1[(2 * bp + 1) * 16 + t] * 0.17677669529663687f);
  }
  for (int i = threadIdx.x; i < 36 * 32; i += 256) {
    int ct = i >> 5, l = i & 31;
    int q = l >> 4, m = l & 15;
    int col = ct * 16 + m;
    const float S = 0.051031036307982884f;          // 1/sqrt16/sqrt24
    uint4 v;
    v.x = packh2(Wv2[(q * 8 + 0) * 576 + col] * S, Wv2[(q * 8 + 1) * 576 + col] * S);
    v.y = packh2(Wv2[(q * 8 + 2) * 576 + col] * S, Wv2[(q * 8 + 3) * 576 + col] * S);
    v.z = packh2(Wv2[(q * 8 + 4) * 576 + col] * S, Wv2[(q * 8 + 5) * 576 + col] * S);
    v.w = packh2(Wv2[(q * 8 + 6) * 576 + col] * S, Wv2[(q * 8 + 7) * 576 + col] * S);
    BF[i] = v;
  }
  __syncthreads();

  int wave = threadIdx.x >> 6, lane = threadIdx.x & 63;
  int q = lane >> 4, m = lane & 15;
  int slot = blockIdx.x * 256 + threadIdx.x;   // wave covers 64 contiguous slots
  int2 e = sd[slot];
  int s = e.x, d = e.y;

  bool same[6];
#pragma unroll
  for (int k = 0; k < 6; ++k) {
    int dd = __shfl_down(d, 1 << k, 64);
    same[k] = ((lane + (1 << k)) < 64) && (dd == d);
  }
  int dprev = __shfl_up(d, 1, 64);
  bool head = (lane == 0) || (dprev != d);

  f16x2 hp[8]; EdgeGeom g;
  edge_h_pk(pos, s, d, LW1, hp, g);
  float xr[40];
  load_row40(x + 40 * s, xr);
  const float* xs = xr;
  const float* xv = xr + 16;
  float B[8];
#pragma unroll
  for (int i = 0; i < 8; ++i)
    B[i] = fmaf(xv[3 * i], g.vhx, fmaf(xv[3 * i + 1], g.vhy, xv[3 * i + 2] * g.vhz));
  float a = ab[slot];

  // H -> LDS (row e = 16 f16 = 32B), then A-frags per row-tile
  {
    union { uint4 u; f16x2 p[4]; } h0, h1;
#pragma unroll
    for (int k = 0; k < 4; ++k) { h0.p[k] = hp[k]; h1.p[k] = hp[4 + k]; }
    unsigned* hrow = &HT[wave][lane][0];
    *(uint4*)hrow = h0.u;
    *(uint4*)(hrow + 4) = h1.u;
  }
  f16x8v afr[4];
  {
    uint4 z4; z4.x = z4.y = z4.z = z4.w = 0u;
#pragma unroll
    for (int rt = 0; rt < 4; ++rt) {
      const unsigned* src = &HT[wave][rt * 16 + m][(q & 1) * 4];
      uint4 t = *(const uint4*)src;                 // cross-lane read: per-wave in-order LDS
      union { uint4 u; f16x8v v; } cv;
      cv.u = (q < 2) ? t : z4;                      // zero-pad K 16..31
      afr[rt] = cv.v;
    }
  }

  float* op = out + 40 * d;
  uint4 z4; z4.x = z4.y = z4.z = z4.w = 0u;

  // -------- tile runner: 4 MFMA + P round-trip; returns this edge's 16 cols --------
#define RUN_TILE(ct, pr)                                                          \
  {                                                                               \
    uint4 braw = *(const uint4*)&BF[(ct) * 32 + (lane & 31)];                     \
    union { uint4 u; f16x8v v; } bc; bc.u = (q < 2) ? braw : z4;                  \
    f32x4v cz = {0.f, 0.f, 0.f, 0.f};                                             \
    f32x4v c0 = __builtin_amdgcn_mfma_f32_16x16x32_f16(afr[0], bc.v, cz, 0, 0, 0);\
    f32x4v c1 = __builtin_amdgcn_mfma_f32_16x16x32_f16(afr[1], bc.v, cz, 0, 0, 0);\
    f32x4v c2 = __builtin_amdgcn_mfma_f32_16x16x32_f16(afr[2], bc.v, cz, 0, 0, 0);\
    f32x4v c3 = __builtin_amdgcn_mfma_f32_16x16x32_f16(afr[3], bc.v, cz, 0, 0, 0);\
    *(f32x4v*)&PT[wave][m][0 * 16 + q * 4] = c0;                                  \
    *(f32x4v*)&PT[wave][m][1 * 16 + q * 4] = c1;                                  \
    *(f32x4v*)&PT[wave][m][2 * 16 + q * 4] = c2;                                  \
    *(f32x4v*)&PT[wave][m][3 * 16 + q * 4] = c3;                                  \
    _Pragma("unroll")                                                             \
    for (int o = 0; o < 16; ++o) (pr)[o] = PT[wave][o][lane];                     \
  }

  // -------- phase A: out_s (cols 0..255 xs-part, 256..383 B-part) --------
  float outs[16];
#pragma unroll
  for (int o = 0; o < 16; ++o) outs[o] = 0.f;
#pragma unroll
  for (int ct = 0; ct < 16; ++ct) {
    float pr[16];
    RUN_TILE(ct, pr)
    float xi = xs[ct];
#pragma unroll
    for (int o = 0; o < 16; ++o) outs[o] = fmaf(xi, pr[o], outs[o]);
  }
#pragma unroll
  for (int ct = 16; ct < 24; ++ct) {
    float pr[16];
    RUN_TILE(ct, pr)
    float bi = B[ct - 16];
#pragma unroll
    for (int o = 0; o < 16; ++o) outs[o] = fmaf(bi, pr[o], outs[o]);
  }
#pragma unroll
  for (int o = 0; o < 16; ++o) {
    float v = a * outs[o];
#pragma unroll
    for (int k = 0; k < 6; ++k) {
      float ov = __shfl_down(v, 1 << k, 64);
      v += same[k] ? ov : 0.f;
    }
    if (head) atomicAdd(op + o, v);
  }

  // -------- phase B: s1 (cols 384..511: i*8+o, i<16) --------
  float s1[8], s2x[8], s2y[8], s2z[8];
#pragma unroll
  for (int o = 0; o < 8; ++o) { s1[o] = 0.f; s2x[o] = 0.f; s2y[o] = 0.f; s2z[o] = 0.f; }
#pragma unroll
  for (int ct = 24; ct < 32; ++ct) {
    float pr[16];
    RUN_TILE(ct, pr)
    int i0 = 2 * (ct - 24), i1 = i0 + 1;
    float x0 = xs[i0], x1 = xs[i1];
#pragma unroll
    for (int o = 0; o < 8; ++o) s1[o] = fmaf(x0, pr[o], fmaf(x1, pr[o + 8], s1[o]));
  }
  // -------- phase C: s2 (cols 512..575: i*8+o, i<8) --------
#pragma unroll
  for (int ct = 32; ct < 36; ++ct) {
    float pr[16];
    RUN_TILE(ct, pr)
    int i0 = 2 * (ct - 32), i1 = i0 + 1;
#pragma unroll
    for (int o = 0; o < 8; ++o) {
      float w0 = pr[o], w1 = pr[o + 8];
      s2x[o] = fmaf(xv[3 * i0],     w0, fmaf(xv[3 * i1],     w1, s2x[o]));
      s2y[o] = fmaf(xv[3 * i0 + 1], w0, fmaf(xv[3 * i1 + 1], w1, s2y[o]));
      s2z[o] = fmaf(xv[3 * i0 + 2], w0, fmaf(xv[3 * i1 + 2], w1, s2z[o]));
    }
  }
#pragma unroll
  for (int o = 0; o < 8; ++o) {
    float vc[3];
    vc[0] = a * fmaf(g.y1x, s1[o], s2x[o]);
    vc[1] = a * fmaf(g.y1y, s1[o], s2y[o]);
    vc[2] = a * fmaf(g.y1z, s1[o], s2z[o]);
#pragma unroll
    for (int c = 0; c < 3; ++c) {
      float v = vc[c];
#pragma unroll
      for (int k = 0; k < 6; ++k) {
        float ov = __shfl_down(v, 1 << k, 64);
        v += same[k] ? ov : 0.f;
      }
      if (head) atomicAdd(op + 16 + 3 * o + c, v);
    }
  }
#undef RUN_TILE
}

extern "C" void kernel_launch(void* const* d_in, const int* in_sizes, int n_in,
                              void* d_out, int out_size, void* d_ws, size_t ws_size,
                              hipStream_t stream) {
  (void)in_sizes; (void)n_in; (void)out_size; (void)ws_size;
  const float* pos  = (const float*)d_in[0];
  const float* x    = (const float*)d_in[1];
  const float* Wq_s = (const float*)d_in[2];
  const float* Wq_v = (const float*)d_in[3];
  const float* Wk1  = (const float*)d_in[4];
  const float* Wk2  = (const float*)d_in[5];
  const float* Wv1  = (const float*)d_in[6];
  const float* Wv2  = (const float*)d_in[7];
  const float* Wss  = (const float*)d_in[8];
  const float* Wvv  = (const float*)d_in[9];
  const int* esrc = (const int*)d_in[10];
  const int* edst = (const int*)d_in[11];
  int*   wsi  = (int*)d_ws;
  float* wsf  = (float*)d_ws;
  float* out  = (float*)d_out;

  int2*  sd    = (int2*)(wsi + OFF_SD);
  float* simb  = wsf + OFF_SIMB;
  int*   cnt   = wsi + OFF_CNT;
  int*   start = wsi + OFF_START;
  int*   cur   = wsi + OFF_CUR;

  hipMemsetAsync(cnt, 0, (size_t)N_NODES * sizeof(int), stream);
  hipMemsetAsync(out, 0, (size_t)(N_NODES * 40) * sizeof(float), stream);
  k_hist<<<1000, 256, 0, stream>>>(edst, cnt);
  k_scan<<<1, 1024, 0, stream>>>(cnt, start, cur);
  k_fill<<<1000, 256, 0, stream>>>(esrc, edst, cur, sd);
  k_edge1<<<1000, 256, 0, stream>>>(pos, x, Wq_s, Wq_v, Wk1, Wk2, Wss, Wvv, sd, simb);
  k_norm<<<63, 256, 0, stream>>>(start, simb);
  k_edge2<<<1000, 256, 0, stream>>>(pos, x, Wv1, Wv2, sd, simb, out);
}

// Round 16
// 258.014 us; speedup vs baseline: 1.4567x; 1.0727x over previous
//
#include <hip/hip_runtime.h>
#include <hip/hip_bf16.h>

#define N_NODES 16000
#define N_EDGES 256000

// ---- workspace layout (4-byte units) — total 834436*4B = 3.34 MB ----
#define OFF_SD     0          // int2  256000  (src,dst) per CSR slot, sorted by dst
#define OFF_SIMB   512000     // float 256000  raw sim -> normalized a (in place)
#define OFF_CNT    768000     // int   16000   per-dst degree
#define OFF_START  784000     // int   16001   CSR row offsets
#define OFF_CUR    800001     // int   16000   fill cursors
#define OFF_WB     816004     // f16   36864   WZ weights in B-fragment order (18432 dwords)

typedef _Float16 f16x2 __attribute__((ext_vector_type(2)));
typedef _Float16 f16x8v __attribute__((ext_vector_type(8)));
typedef float f32x4v __attribute__((ext_vector_type(4)));

__device__ __forceinline__ float fdot2f(f16x2 a, f16x2 b, float c) {
#if __has_builtin(__builtin_amdgcn_fdot2)
  return __builtin_amdgcn_fdot2(a, b, c, false);
#else
  return fmaf((float)a.x, (float)b.x, fmaf((float)a.y, (float)b.y, c));
#endif
}

__device__ __forceinline__ unsigned packh2(float a, float b) {
  union { unsigned u; f16x2 p; } v;
  v.p.x = (_Float16)a; v.p.y = (_Float16)b;
  return v.u;
}

// dot of h (8 packed f16 pairs) with a 16-f16 LDS column — used by k_edge1 (r11)
__device__ __forceinline__ float dot16h(const f16x2* hp, const unsigned* w) {
  union { uint4 u; f16x2 p[4]; } a, b;
  a.u = *(const uint4*)(w);
  b.u = *(const uint4*)(w + 4);
  float r = 0.f;
  r = fdot2f(hp[0], a.p[0], r);
  r = fdot2f(hp[1], a.p[1], r);
  r = fdot2f(hp[2], a.p[2], r);
  r = fdot2f(hp[3], a.p[3], r);
  r = fdot2f(hp[4], b.p[0], r);
  r = fdot2f(hp[5], b.p[1], r);
  r = fdot2f(hp[6], b.p[2], r);
  r = fdot2f(hp[7], b.p[3], r);
  return r;
}

__device__ __forceinline__ void load_row40(const float* __restrict__ p, float* xr) {
  const float4* rp = reinterpret_cast<const float4*>(p);
#pragma unroll
  for (int q = 0; q < 10; ++q) {
    float4 f = rp[q];
    xr[4 * q + 0] = f.x; xr[4 * q + 1] = f.y; xr[4 * q + 2] = f.z; xr[4 * q + 3] = f.w;
  }
}

struct EdgeGeom { float vhx, vhy, vhz, y1x, y1y, y1z; };

// geometry + radial basis + h = silu(rad @ W1n), packed as 8 f16 pairs (r11-validated)
__device__ __forceinline__ void edge_h_pk(const float* __restrict__ pos, int s, int d,
                                          const unsigned* W1, f16x2* hp, EdgeGeom& g) {
  float vx = pos[3 * d + 0] - pos[3 * s + 0];
  float vy = pos[3 * d + 1] - pos[3 * s + 1];
  float vz = pos[3 * d + 2] - pos[3 * s + 2];
  float dist = sqrtf(fmaf(vx, vx, fmaf(vy, vy, vz * vz)));
  float dsafe = fmaxf(dist, 1e-6f);
  float rinv = 1.0f / dsafe;
  g.vhx = vx * rinv; g.vhy = vy * rinv; g.vhz = vz * rinv;
  g.y1x = 1.7320508075688772f * g.vhx;
  g.y1y = 1.7320508075688772f * g.vhy;
  g.y1z = 1.7320508075688772f * g.vhz;
  float pre[16];
#pragma unroll
  for (int t = 0; t < 16; ++t) pre[t] = 0.f;
  float sx, cx;
  sincosf(1.2566370614359172f * dsafe, &sx, &cx);
  cx = fminf(1.f, fmaxf(-1.f, cx));
  float twoc = 2.f * cx;
  float sprev = 0.f, scur = sx;
  float rscale = (dist < 2.5f) ? (5.059644256269407f * rinv) : 0.f;
#pragma unroll
  for (int bp = 0; bp < 16; ++bp) {
    float r0 = rscale * scur;
    float sn = fmaf(twoc, scur, -sprev); sprev = scur; scur = sn;
    float r1 = rscale * scur;
    sn = fmaf(twoc, scur, -sprev); sprev = scur; scur = sn;
    union { unsigned u; f16x2 p; } rp; rp.p.x = (_Float16)r0; rp.p.y = (_Float16)r1;
    union { uint4 u[4]; f16x2 p[16]; } w;
    w.u[0] = *(const uint4*)(W1 + bp * 16);
    w.u[1] = *(const uint4*)(W1 + bp * 16 + 4);
    w.u[2] = *(const uint4*)(W1 + bp * 16 + 8);
    w.u[3] = *(const uint4*)(W1 + bp * 16 + 12);
#pragma unroll
    for (int t = 0; t < 16; ++t) pre[t] = fdot2f(rp.p, w.p[t], pre[t]);
  }
#pragma unroll
  for (int tp = 0; tp < 8; ++tp) {
    float h0 = pre[2 * tp]     / (1.f + __expf(-pre[2 * tp]));
    float h1 = pre[2 * tp + 1] / (1.f + __expf(-pre[2 * tp + 1]));
    hp[tp].x = (_Float16)h0; hp[tp].y = (_Float16)h1;
  }
}

// ================= CSR build =================
__global__ void k_hist(const int* __restrict__ edst, int* __restrict__ cnt) {
  int e = blockIdx.x * 256 + threadIdx.x;
  atomicAdd(&cnt[edst[e]], 1);
}

__global__ void __launch_bounds__(1024) k_scan(const int* __restrict__ cnt,
                                               int* __restrict__ start, int* __restrict__ cur) {
  __shared__ int part[1024];
  int t = threadIdx.x;
  int base = t * 16;
  int local[16];
  int sum = 0;
#pragma unroll
  for (int i = 0; i < 16; ++i) {
    int idx = base + i;
    int c = (idx < N_NODES) ? cnt[idx] : 0;
    local[i] = sum; sum += c;
  }
  part[t] = sum;
  __syncthreads();
  for (int off = 1; off < 1024; off <<= 1) {
    int v = (t >= off) ? part[t - off] : 0;
    __syncthreads();
    part[t] += v;
    __syncthreads();
  }
  int prev = (t == 0) ? 0 : part[t - 1];
#pragma unroll
  for (int i = 0; i < 16; ++i) {
    int idx = base + i;
    if (idx < N_NODES) { int st = prev + local[i]; start[idx] = st; cur[idx] = st; }
  }
  if (t == 0) start[N_NODES] = N_EDGES;
}

__global__ void k_fill(const int* __restrict__ esrc, const int* __restrict__ edst,
                       int* __restrict__ cur, int2* __restrict__ sd) {
  int e = blockIdx.x * 256 + threadIdx.x;
  int d = edst[e];
  int slot = atomicAdd(&cur[d], 1);
  sd[slot] = make_int2(esrc[e], d);
}

// ============ prepack WZ[768][48] (V-side) into B-fragment order, f16, scaled ============
// WB[((kk*3+ct)*64 + lane)*8 + j] = WZ[32kk + 8(lane>>4) + j][16ct + (lane&15)]
__global__ void k_prepB(const float* __restrict__ Wv2, unsigned short* __restrict__ WB) {
  int idx = blockIdx.x * 256 + threadIdx.x;   // 144*256 = 36864 exact
  int j = idx & 7;
  int lane = (idx >> 3) & 63;
  int t3 = idx >> 9;
  int ct = t3 % 3, kk = t3 / 3;
  int q = lane >> 4, m = lane & 15;
  int row = 32 * kk + 8 * q + j;
  int col = 16 * ct + m;
  int t = row & 15;
  float v = 0.f;
  if (row < 256) {                       // Z = h (x) xs
    int i = row >> 4;
    if (col < 16)      v = Wv2[t * 576 + i * 16 + col];          // out_s
    else if (col < 24) v = Wv2[t * 576 + 384 + i * 8 + (col - 16)]; // s1
  } else if (row < 384) {                // Z = h (x) B
    int i = (row - 256) >> 4;
    if (col < 16)      v = Wv2[t * 576 + 256 + i * 16 + col];    // out_s (B part)
  } else {                               // Z = h (x) xv_c  (c = part)
    int part = (row - 384) >> 7;
    int i = ((row - 384) & 127) >> 4;
    int cb = 24 + 8 * part;
    if (col >= cb && col < cb + 8) v = Wv2[t * 576 + 512 + i * 8 + (col - cb)]; // s2c
  }
  union { unsigned short u; _Float16 h; } cv;
  cv.h = (_Float16)(v * 0.051031036307982884f);   // 1/sqrt16/sqrt24
  WB[idx] = cv.u;
}

// ================= pass 1 (r11-exact): q + k TP (f16 weights) + raw sim =================
__global__ void __launch_bounds__(256) k_edge1(
    const float* __restrict__ pos, const float* __restrict__ x,
    const float* __restrict__ Wq_s, const float* __restrict__ Wq_v,
    const float* __restrict__ Wk1, const float* __restrict__ Wk2,
    const float* __restrict__ Wss, const float* __restrict__ Wvv,
    const int2* __restrict__ sd, float* __restrict__ simb) {
  __shared__ __align__(16) unsigned Lw[2560];
  __shared__ float Ls[240];
  for (int i = threadIdx.x; i < 2560; i += 256) {
    unsigned v;
    if (i < 256) {
      int bp = i >> 4, t = i & 15;
      v = packh2(Wk1[(2 * bp) * 16 + t] * 0.17677669529663687f,
                 Wk1[(2 * bp + 1) * 16 + t] * 0.17677669529663687f);
    } else {
      int j = i - 256; int col = j >> 3, tp = j & 7;
      v = packh2(Wk2[(2 * tp) * 288 + col] * 0.051031036307982884f,
                 Wk2[(2 * tp + 1) * 288 + col] * 0.051031036307982884f);
    }
    Lw[i] = v;
  }
  for (int i = threadIdx.x; i < 240; i += 256) {
    float v;
    if (i < 128)      v = Wq_s[i] * 0.25f;
    else if (i < 160) v = Wq_v[i - 128] * 0.3535533905932738f;
    else if (i < 224) v = Wss[i - 160] * 0.11180339887498948f;
    else              v = Wvv[i - 224] * 0.06454972243679028f;
    Ls[i] = v;
  }
  __syncthreads();

  int slot = blockIdx.x * 256 + threadIdx.x;
  int2 e = sd[slot];
  int s = e.x, d = e.y;
  f16x2 hp[8]; EdgeGeom g;
  edge_h_pk(pos, s, d, Lw, hp, g);

  float qd[8], qvd[12];
  {
    float xd[40];
    load_row40(x + 40 * d, xd);
#pragma unroll
    for (int o = 0; o < 8; ++o) qd[o] = 0.f;
#pragma unroll
    for (int i = 0; i < 16; ++i)
#pragma unroll
      for (int o = 0; o < 8; ++o) qd[o] = fmaf(xd[i], Ls[8 * i + o], qd[o]);
#pragma unroll
    for (int k = 0; k < 12; ++k) qvd[k] = 0.f;
#pragma unroll
    for (int i = 0; i < 8; ++i)
#pragma unroll
      for (int o = 0; o < 4; ++o)
#pragma unroll
        for (int c = 0; c < 3; ++c)
          qvd[3 * o + c] = fmaf(xd[16 + 3 * i + c], Ls[128 + 4 * i + o], qvd[3 * o + c]);
  }

  float xr[40];
  load_row40(x + 40 * s, xr);
  const float* xs = xr;
  const float* xv = xr + 16;
  float B[8];
#pragma unroll
  for (int i = 0; i < 8; ++i)
    B[i] = fmaf(xv[3 * i], g.vhx, fmaf(xv[3 * i + 1], g.vhy, xv[3 * i + 2] * g.vhz));

  const unsigned* W2 = Lw + 256;
  float ks[8];
#pragma unroll
  for (int o = 0; o < 8; ++o) {
    float acc = 0.f;
#pragma unroll
    for (int i = 0; i < 16; ++i) acc = fmaf(xs[i], dot16h(hp, W2 + ((i * 8 + o) << 3)), acc);
#pragma unroll
    for (int i = 0; i < 8; ++i)  acc = fmaf(B[i], dot16h(hp, W2 + ((128 + i * 8 + o) << 3)), acc);
    ks[o] = acc;
  }
  float kv[12];
#pragma unroll
  for (int o = 0; o < 4; ++o) {
    float s1 = 0.f;
#pragma unroll
    for (int i = 0; i < 16; ++i) s1 = fmaf(xs[i], dot16h(hp, W2 + ((192 + i * 4 + o) << 3)), s1);
    float s2x = 0.f, s2y = 0.f, s2z = 0.f;
#pragma unroll
    for (int i = 0; i < 8; ++i) {
      float w = dot16h(hp, W2 + ((256 + i * 4 + o) << 3));
      s2x = fmaf(xv[3 * i], w, s2x);
      s2y = fmaf(xv[3 * i + 1], w, s2y);
      s2z = fmaf(xv[3 * i + 2], w, s2z);
    }
    kv[3 * o]     = fmaf(g.y1x, s1, s2x);
    kv[3 * o + 1] = fmaf(g.y1y, s1, s2y);
    kv[3 * o + 2] = fmaf(g.y1z, s1, s2z);
  }

  float sim = 0.f;
#pragma unroll
  for (int jj = 0; jj < 8; ++jj) {
    float t = 0.f;
#pragma unroll
    for (int i = 0; i < 8; ++i) t = fmaf(qd[i], Ls[160 + 8 * i + jj], t);
    sim = fmaf(t, ks[jj], sim);
  }
#pragma unroll
  for (int jj = 0; jj < 4; ++jj)
#pragma unroll
    for (int c = 0; c < 3; ++c) {
      float t = 0.f;
#pragma unroll
      for (int i = 0; i < 4; ++i) t = fmaf(qvd[3 * i + c], Ls[224 + 4 * i + jj], t);
      sim = fmaf(t, kv[3 * jj + c], sim);
    }
  simb[slot] = sim;
}

// ================= exact per-dst softmax =================
__global__ void k_norm(const int* __restrict__ start, float* __restrict__ simb) {
  int n = blockIdx.x * 256 + threadIdx.x;
  if (n >= N_NODES) return;
  int a = start[n], b = start[n + 1];
  if (a == b) return;
  float m = -3.4e38f;
  for (int j = a; j < b; ++j) m = fmaxf(m, simb[j]);
  float Z = 0.f;
  for (int j = a; j < b; ++j) { float t = __expf(simb[j] - m); simb[j] = t; Z += t; }
  float inv = 1.f / Z;
  for (int j = a; j < b; ++j) simb[j] *= inv;
}

// ======= pass 2: Z-GEMM MFMA — P[64][48] = Z[64][768] x WZ[768][48] per wave =======
// A-frag: lane(q,m) holds Z[16rt+m][k=8q+j] (m120-verified, r15-validated end-to-end)
// B-frag: lane(q,m) holds WZ[k=8q+j][n=16ct+m] from global WB (r15-validated duality)
// C/D:    lane(q,m) holds D[row=4q+r][col=m] (m89-verified)
#define ZTW 20   // dwords per ZT row (40 f16: 32 used + 8 pad -> 2-way-free banks)
#define CTW 52   // floats per CT row (48 used + 4 pad -> 2-way-free banks)
__global__ void __launch_bounds__(256) k_edge2(
    const float* __restrict__ pos, const float* __restrict__ x,
    const float* __restrict__ Wv1, const unsigned short* __restrict__ WB,
    const int2* __restrict__ sd, const float* __restrict__ ab, float* __restrict__ out) {
  __shared__ __align__(16) unsigned LW1[256];
  __shared__ __align__(16) float SM[4][64 * CTW];   // per-wave region: ZT (k-loop) then CT (epilogue)

  for (int i = threadIdx.x; i < 256; i += 256) {
    int bp = i >> 4, t = i & 15;
    LW1[i] = packh2(Wv1[(2 * bp) * 16 + t] * 0.17677669529663687f,
                    Wv1[(2 * bp + 1) * 16 + t] * 0.17677669529663687f);
  }
  __syncthreads();

  int wave = threadIdx.x >> 6, lane = threadIdx.x & 63;
  int q = lane >> 4, m = lane & 15;
  int slot = blockIdx.x * 256 + threadIdx.x;   // wave = 64 contiguous slots
  int2 e = sd[slot];
  int s = e.x, d = e.y;

  bool same[6];
#pragma unroll
  for (int k = 0; k < 6; ++k) {
    int dd = __shfl_down(d, 1 << k, 64);
    same[k] = ((lane + (1 << k)) < 64) && (dd == d);
  }
  int dprev = __shfl_up(d, 1, 64);
  bool head = (lane == 0) || (dprev != d);

  f16x2 hp[8]; EdgeGeom g;
  edge_h_pk(pos, s, d, LW1, hp, g);
  float xr[40];
  load_row40(x + 40 * s, xr);
  float xs[16];
#pragma unroll
  for (int i = 0; i < 16; ++i) xs[i] = xr[i];
  float Bv[8];
#pragma unroll
  for (int i = 0; i < 8; ++i)
    Bv[i] = fmaf(xr[16 + 3 * i], g.vhx, fmaf(xr[17 + 3 * i], g.vhy, xr[18 + 3 * i] * g.vhz));
  f16x2 cxv[3][4];   // [c][pair p] = (xv[3*2p+c], xv[3*(2p+1)+c])
#pragma unroll
  for (int p = 0; p < 4; ++p)
#pragma unroll
    for (int c = 0; c < 3; ++c) {
      cxv[c][p].x = (_Float16)xr[16 + 3 * (2 * p) + c];
      cxv[c][p].y = (_Float16)xr[16 + 3 * (2 * p + 1) + c];
    }
  float a = ab[slot];

  unsigned* zt = (unsigned*)&SM[wave][0];
  const uint4* WBq = (const uint4*)WB;

  f32x4v acc[4][3];
#pragma unroll
  for (int rt = 0; rt < 4; ++rt)
#pragma unroll
    for (int ct = 0; ct < 3; ++ct) { f32x4v z = {0.f, 0.f, 0.f, 0.f}; acc[rt][ct] = z; }

#pragma unroll
  for (int kk = 0; kk < 24; ++kk) {
    // coefficient splats for the two i's of this k-tile (compile-time branch)
    f16x2 sp0, sp1;
    if (kk < 8) {
      sp0.x = sp0.y = (_Float16)xs[2 * kk];
      sp1.x = sp1.y = (_Float16)xs[2 * kk + 1];
    } else if (kk < 12) {
      sp0.x = sp0.y = (_Float16)Bv[2 * (kk - 8)];
      sp1.x = sp1.y = (_Float16)Bv[2 * (kk - 8) + 1];
    } else {
      int part = (kk - 12) >> 2, p = (kk - 12) & 3;
      sp0.x = sp0.y = cxv[part][p].x;
      sp1.x = sp1.y = cxv[part][p].y;
    }
    // Z chunk: 32 f16 = {h*c0 (16), h*c1 (16)}
    union { uint4 u[4]; f16x2 z[16]; } Z;
#pragma unroll
    for (int t = 0; t < 8; ++t) { Z.z[t] = hp[t] * sp0; Z.z[8 + t] = hp[t] * sp1; }
    uint4* zrow = (uint4*)(zt + lane * ZTW);
    zrow[0] = Z.u[0]; zrow[1] = Z.u[1]; zrow[2] = Z.u[2]; zrow[3] = Z.u[3];
    // A-frags (cross-lane via per-wave in-order LDS)
    union { uint4 u; f16x8v v; } af[4];
#pragma unroll
    for (int rt = 0; rt < 4; ++rt)
      af[rt].u = *(const uint4*)(zt + (16 * rt + m) * ZTW + 4 * q);
    // B-frags from global (L2-hot) + MFMA
#pragma unroll
    for (int ct = 0; ct < 3; ++ct) {
      union { uint4 u; f16x8v v; } bf;
      bf.u = WBq[(kk * 3 + ct) * 64 + lane];
#pragma unroll
      for (int rt = 0; rt < 4; ++rt)
        acc[rt][ct] = __builtin_amdgcn_mfma_f32_16x16x32_f16(af[rt].v, bf.v, acc[rt][ct], 0, 0, 0);
    }
  }

  // C -> per-edge P[48] via LDS transpose (reuses ZT region; per-wave in-order)
  float* ctb = &SM[wave][0];
#pragma unroll
  for (int rt = 0; rt < 4; ++rt)
#pragma unroll
    for (int ct = 0; ct < 3; ++ct)
#pragma unroll
      for (int r = 0; r < 4; ++r)
        ctb[(16 * rt + 4 * q + r) * CTW + (m + 16 * ct)] = acc[rt][ct][r];
  float P[48];
#pragma unroll
  for (int b = 0; b < 12; ++b) {
    float4 f = *(const float4*)(ctb + lane * CTW + 4 * b);
    P[4 * b] = f.x; P[4 * b + 1] = f.y; P[4 * b + 2] = f.z; P[4 * b + 3] = f.w;
  }

  // r11-exact epilogue
  float* op = out + 40 * d;
#pragma unroll
  for (int o = 0; o < 16; ++o) {
    float v = a * P[o];
#pragma unroll
    for (int k = 0; k < 6; ++k) {
      float ov = __shfl_down(v, 1 << k, 64);
      v += same[k] ? ov : 0.f;
    }
    if (head) atomicAdd(op + o, v);
  }
#pragma unroll
  for (int o = 0; o < 8; ++o) {
    float s1v = P[16 + o];
    float vc[3];
    vc[0] = a * fmaf(g.y1x, s1v, P[24 + o]);
    vc[1] = a * fmaf(g.y1y, s1v, P[32 + o]);
    vc[2] = a * fmaf(g.y1z, s1v, P[40 + o]);
#pragma unroll
    for (int c = 0; c < 3; ++c) {
      float v = vc[c];
#pragma unroll
      for (int k = 0; k < 6; ++k) {
        float ov = __shfl_down(v, 1 << k, 64);
        v += same[k] ? ov : 0.f;
      }
      if (head) atomicAdd(op + 16 + 3 * o + c, v);
    }
  }
}

extern "C" void kernel_launch(void* const* d_in, const int* in_sizes, int n_in,
                              void* d_out, int out_size, void* d_ws, size_t ws_size,
                              hipStream_t stream) {
  (void)in_sizes; (void)n_in; (void)out_size; (void)ws_size;
  const float* pos  = (const float*)d_in[0];
  const float* x    = (const float*)d_in[1];
  const float* Wq_s = (const float*)d_in[2];
  const float* Wq_v = (const float*)d_in[3];
  const float* Wk1  = (const float*)d_in[4];
  const float* Wk2  = (const float*)d_in[5];
  const float* Wv1  = (const float*)d_in[6];
  const float* Wv2  = (const float*)d_in[7];
  const float* Wss  = (const float*)d_in[8];
  const float* Wvv  = (const float*)d_in[9];
  const int* esrc = (const int*)d_in[10];
  const int* edst = (const int*)d_in[11];
  int*   wsi  = (int*)d_ws;
  float* wsf  = (float*)d_ws;
  float* out  = (float*)d_out;

  int2*  sd    = (int2*)(wsi + OFF_SD);
  float* simb  = wsf + OFF_SIMB;
  int*   cnt   = wsi + OFF_CNT;
  int*   start = wsi + OFF_START;
  int*   cur   = wsi + OFF_CUR;
  unsigned short* WB = (unsigned short*)(wsf + OFF_WB);

  hipMemsetAsync(cnt, 0, (size_t)N_NODES * sizeof(int), stream);
  hipMemsetAsync(out, 0, (size_t)(N_NODES * 40) * sizeof(float), stream);
  k_prepB<<<144, 256, 0, stream>>>(Wv2, WB);
  k_hist<<<1000, 256, 0, stream>>>(edst, cnt);
  k_scan<<<1, 1024, 0, stream>>>(cnt, start, cur);
  k_fill<<<1000, 256, 0, stream>>>(esrc, edst, cur, sd);
  k_edge1<<<1000, 256, 0, stream>>>(pos, x, Wq_s, Wq_v, Wk1, Wk2, Wss, Wvv, sd, simb);
  k_norm<<<63, 256, 0, stream>>>(start, simb);
  k_edge2<<<1000, 256, 0, stream>>>(pos, x, Wv1, WB, sd, simb, out);
}

// Round 17
// 247.240 us; speedup vs baseline: 1.5202x; 1.0436x over previous
//
#include <hip/hip_runtime.h>
#include <hip/hip_bf16.h>

#define N_NODES 16000
#define N_EDGES 256000

// ---- workspace layout (4-byte units) — total 846724*4B = 3.39 MB ----
#define OFF_SD     0          // int2  256000  (src,dst) per CSR slot, sorted by dst
#define OFF_SIMB   512000     // float 256000  raw sim -> normalized a (in place)
#define OFF_CNT    768000     // int   16000   per-dst degree
#define OFF_START  784000     // int   16001   CSR row offsets
#define OFF_CUR    800001     // int   16000   fill cursors
#define OFF_WB     816004     // f16   36864   WZ-V weights, B-frag order (18432 dwords)
#define OFF_WBK    834436     // f16   24576   WZ-K weights, B-frag order (12288 dwords)

typedef _Float16 f16x2 __attribute__((ext_vector_type(2)));
typedef _Float16 f16x8v __attribute__((ext_vector_type(8)));
typedef float f32x4v __attribute__((ext_vector_type(4)));

__device__ __forceinline__ float fdot2f(f16x2 a, f16x2 b, float c) {
#if __has_builtin(__builtin_amdgcn_fdot2)
  return __builtin_amdgcn_fdot2(a, b, c, false);
#else
  return fmaf((float)a.x, (float)b.x, fmaf((float)a.y, (float)b.y, c));
#endif
}

__device__ __forceinline__ unsigned packh2(float a, float b) {
  union { unsigned u; f16x2 p; } v;
  v.p.x = (_Float16)a; v.p.y = (_Float16)b;
  return v.u;
}

__device__ __forceinline__ void load_row40(const float* __restrict__ p, float* xr) {
  const float4* rp = reinterpret_cast<const float4*>(p);
#pragma unroll
  for (int q = 0; q < 10; ++q) {
    float4 f = rp[q];
    xr[4 * q + 0] = f.x; xr[4 * q + 1] = f.y; xr[4 * q + 2] = f.z; xr[4 * q + 3] = f.w;
  }
}

struct EdgeGeom { float vhx, vhy, vhz, y1x, y1y, y1z; };

// geometry + radial basis + h = silu(rad @ W1n), packed as 8 f16 pairs (r11-validated)
__device__ __forceinline__ void edge_h_pk(const float* __restrict__ pos, int s, int d,
                                          const unsigned* W1, f16x2* hp, EdgeGeom& g) {
  float vx = pos[3 * d + 0] - pos[3 * s + 0];
  float vy = pos[3 * d + 1] - pos[3 * s + 1];
  float vz = pos[3 * d + 2] - pos[3 * s + 2];
  float dist = sqrtf(fmaf(vx, vx, fmaf(vy, vy, vz * vz)));
  float dsafe = fmaxf(dist, 1e-6f);
  float rinv = 1.0f / dsafe;
  g.vhx = vx * rinv; g.vhy = vy * rinv; g.vhz = vz * rinv;
  g.y1x = 1.7320508075688772f * g.vhx;
  g.y1y = 1.7320508075688772f * g.vhy;
  g.y1z = 1.7320508075688772f * g.vhz;
  float pre[16];
#pragma unroll
  for (int t = 0; t < 16; ++t) pre[t] = 0.f;
  float sx, cx;
  sincosf(1.2566370614359172f * dsafe, &sx, &cx);
  cx = fminf(1.f, fmaxf(-1.f, cx));
  float twoc = 2.f * cx;
  float sprev = 0.f, scur = sx;
  float rscale = (dist < 2.5f) ? (5.059644256269407f * rinv) : 0.f;
#pragma unroll
  for (int bp = 0; bp < 16; ++bp) {
    float r0 = rscale * scur;
    float sn = fmaf(twoc, scur, -sprev); sprev = scur; scur = sn;
    float r1 = rscale * scur;
    sn = fmaf(twoc, scur, -sprev); sprev = scur; scur = sn;
    union { unsigned u; f16x2 p; } rp; rp.p.x = (_Float16)r0; rp.p.y = (_Float16)r1;
    union { uint4 u[4]; f16x2 p[16]; } w;
    w.u[0] = *(const uint4*)(W1 + bp * 16);
    w.u[1] = *(const uint4*)(W1 + bp * 16 + 4);
    w.u[2] = *(const uint4*)(W1 + bp * 16 + 8);
    w.u[3] = *(const uint4*)(W1 + bp * 16 + 12);
#pragma unroll
    for (int t = 0; t < 16; ++t) pre[t] = fdot2f(rp.p, w.p[t], pre[t]);
  }
#pragma unroll
  for (int tp = 0; tp < 8; ++tp) {
    float h0 = pre[2 * tp]     / (1.f + __expf(-pre[2 * tp]));
    float h1 = pre[2 * tp + 1] / (1.f + __expf(-pre[2 * tp + 1]));
    hp[tp].x = (_Float16)h0; hp[tp].y = (_Float16)h1;
  }
}

// ================= CSR build =================
__global__ void k_hist(const int* __restrict__ edst, int* __restrict__ cnt) {
  int e = blockIdx.x * 256 + threadIdx.x;
  atomicAdd(&cnt[edst[e]], 1);
}

__global__ void __launch_bounds__(1024) k_scan(const int* __restrict__ cnt,
                                               int* __restrict__ start, int* __restrict__ cur) {
  __shared__ int part[1024];
  int t = threadIdx.x;
  int base = t * 16;
  int local[16];
  int sum = 0;
#pragma unroll
  for (int i = 0; i < 16; ++i) {
    int idx = base + i;
    int c = (idx < N_NODES) ? cnt[idx] : 0;
    local[i] = sum; sum += c;
  }
  part[t] = sum;
  __syncthreads();
  for (int off = 1; off < 1024; off <<= 1) {
    int v = (t >= off) ? part[t - off] : 0;
    __syncthreads();
    part[t] += v;
    __syncthreads();
  }
  int prev = (t == 0) ? 0 : part[t - 1];
#pragma unroll
  for (int i = 0; i < 16; ++i) {
    int idx = base + i;
    if (idx < N_NODES) { int st = prev + local[i]; start[idx] = st; cur[idx] = st; }
  }
  if (t == 0) start[N_NODES] = N_EDGES;
}

__global__ void k_fill(const int* __restrict__ esrc, const int* __restrict__ edst,
                       int* __restrict__ cur, int2* __restrict__ sd) {
  int e = blockIdx.x * 256 + threadIdx.x;
  int d = edst[e];
  int slot = atomicAdd(&cur[d], 1);
  sd[slot] = make_int2(esrc[e], d);
}

// ============ prepack WZ-V[768][48] into B-fragment order, f16, scaled (r16-validated) ========
__global__ void k_prepB(const float* __restrict__ Wv2, unsigned short* __restrict__ WB) {
  int idx = blockIdx.x * 256 + threadIdx.x;   // 144*256 = 36864 exact
  int j = idx & 7;
  int lane = (idx >> 3) & 63;
  int t3 = idx >> 9;
  int ct = t3 % 3, kk = t3 / 3;
  int q = lane >> 4, m = lane & 15;
  int row = 32 * kk + 8 * q + j;
  int col = 16 * ct + m;
  int t = row & 15;
  float v = 0.f;
  if (row < 256) {                       // Z = h (x) xs
    int i = row >> 4;
    if (col < 16)      v = Wv2[t * 576 + i * 16 + col];
    else if (col < 24) v = Wv2[t * 576 + 384 + i * 8 + (col - 16)];
  } else if (row < 384) {                // Z = h (x) B
    int i = (row - 256) >> 4;
    if (col < 16)      v = Wv2[t * 576 + 256 + i * 16 + col];
  } else {                               // Z = h (x) xv_c
    int part = (row - 384) >> 7;
    int i = ((row - 384) & 127) >> 4;
    int cb = 24 + 8 * part;
    if (col >= cb && col < cb + 8) v = Wv2[t * 576 + 512 + i * 8 + (col - cb)];
  }
  union { unsigned short u; _Float16 h; } cv;
  cv.h = (_Float16)(v * 0.051031036307982884f);
  WB[idx] = cv.u;
}

// ============ prepack WZ-K[768][24->32] into B-fragment order, f16, scaled ============
// cols: 0..7 ks_j | 8..11 s1_o | 12+4c+o s2_{o,c}
__global__ void k_prepBK(const float* __restrict__ Wk2, unsigned short* __restrict__ WBK) {
  int idx = blockIdx.x * 256 + threadIdx.x;   // 96*256 = 24576 exact
  int j = idx & 7;
  int lane = (idx >> 3) & 63;
  int t2 = idx >> 9;
  int ct = t2 & 1, kk = t2 >> 1;
  int q = lane >> 4, m = lane & 15;
  int row = 32 * kk + 8 * q + j;
  int col = 16 * ct + m;
  int t = row & 15;
  float v = 0.f;
  if (col < 24) {
    if (row < 256) {                     // Z = h (x) xs
      int i = row >> 4;
      if (col < 8)       v = Wk2[t * 288 + i * 8 + col];              // ks (w_ss)
      else if (col < 12) v = Wk2[t * 288 + 192 + i * 4 + (col - 8)];  // s1 (w_sv)
    } else if (row < 384) {              // Z = h (x) B
      int i = (row - 256) >> 4;
      if (col < 8)       v = Wk2[t * 288 + 128 + i * 8 + col];        // ks (w_vv)
    } else {                             // Z = h (x) xv_c
      int c = (row - 384) >> 7;
      int i = ((row - 384) & 127) >> 4;
      int cb = 12 + 4 * c;
      if (col >= cb && col < cb + 4) v = Wk2[t * 288 + 256 + i * 4 + (col - cb)]; // s2 (w_vs)
    }
  }
  union { unsigned short u; _Float16 h; } cv;
  cv.h = (_Float16)(v * 0.051031036307982884f);
  WBK[idx] = cv.u;
}

#define ZTW 20   // dwords per SM row: ZT 32 f16 (16 dw) + pad; CT 16 floats + pad

// ======= pass 1: Z-GEMM MFMA — P[64][24] = Z[64][768] x WZK[768][24] per wave =======
__global__ void __launch_bounds__(256) k_edge1(
    const float* __restrict__ pos, const float* __restrict__ x,
    const float* __restrict__ Wq_s, const float* __restrict__ Wq_v,
    const float* __restrict__ Wk1,
    const float* __restrict__ Wss, const float* __restrict__ Wvv,
    const unsigned short* __restrict__ WBK,
    const int2* __restrict__ sd, float* __restrict__ simb) {
  __shared__ __align__(16) unsigned LW1[256];
  __shared__ float Ls[240];
  __shared__ __align__(16) float SM[4][64 * ZTW];

  for (int i = threadIdx.x; i < 256; i += 256) {
    int bp = i >> 4, t = i & 15;
    LW1[i] = packh2(Wk1[(2 * bp) * 16 + t] * 0.17677669529663687f,
                    Wk1[(2 * bp + 1) * 16 + t] * 0.17677669529663687f);
  }
  for (int i = threadIdx.x; i < 240; i += 256) {
    float v;
    if (i < 128)      v = Wq_s[i] * 0.25f;
    else if (i < 160) v = Wq_v[i - 128] * 0.3535533905932738f;
    else if (i < 224) v = Wss[i - 160] * 0.11180339887498948f;
    else              v = Wvv[i - 224] * 0.06454972243679028f;
    Ls[i] = v;
  }
  __syncthreads();

  int wave = threadIdx.x >> 6, lane = threadIdx.x & 63;
  int q = lane >> 4, m = lane & 15;
  int slot = blockIdx.x * 256 + threadIdx.x;
  int2 e = sd[slot];
  int s = e.x, d = e.y;

  f16x2 hp[8]; EdgeGeom g;
  edge_h_pk(pos, s, d, LW1, hp, g);

  // q-tilde: q contracted with Wss/Wvv (r14-validated math)
  float qts[8], qtv[12];
  {
    float xd[40];
    load_row40(x + 40 * d, xd);
    float qd[8], qvd[12];
#pragma unroll
    for (int o = 0; o < 8; ++o) qd[o] = 0.f;
#pragma unroll
    for (int i = 0; i < 16; ++i)
#pragma unroll
      for (int o = 0; o < 8; ++o) qd[o] = fmaf(xd[i], Ls[8 * i + o], qd[o]);
#pragma unroll
    for (int k = 0; k < 12; ++k) qvd[k] = 0.f;
#pragma unroll
    for (int i = 0; i < 8; ++i)
#pragma unroll
      for (int o = 0; o < 4; ++o)
#pragma unroll
        for (int c = 0; c < 3; ++c)
          qvd[3 * o + c] = fmaf(xd[16 + 3 * i + c], Ls[128 + 4 * i + o], qvd[3 * o + c]);
#pragma unroll
    for (int j = 0; j < 8; ++j) {
      float t = 0.f;
#pragma unroll
      for (int i = 0; i < 8; ++i) t = fmaf(qd[i], Ls[160 + 8 * i + j], t);
      qts[j] = t;
    }
#pragma unroll
    for (int o = 0; o < 4; ++o)
#pragma unroll
      for (int c = 0; c < 3; ++c) {
        float t = 0.f;
#pragma unroll
        for (int i = 0; i < 4; ++i) t = fmaf(qvd[3 * i + c], Ls[224 + 4 * i + o], t);
        qtv[3 * o + c] = t;
      }
  }

  float xr[40];
  load_row40(x + 40 * s, xr);
  float xs[16];
#pragma unroll
  for (int i = 0; i < 16; ++i) xs[i] = xr[i];
  float Bv[8];
#pragma unroll
  for (int i = 0; i < 8; ++i)
    Bv[i] = fmaf(xr[16 + 3 * i], g.vhx, fmaf(xr[17 + 3 * i], g.vhy, xr[18 + 3 * i] * g.vhz));
  f16x2 cxv[3][4];
#pragma unroll
  for (int p = 0; p < 4; ++p)
#pragma unroll
    for (int c = 0; c < 3; ++c) {
      cxv[c][p].x = (_Float16)xr[16 + 3 * (2 * p) + c];
      cxv[c][p].y = (_Float16)xr[16 + 3 * (2 * p + 1) + c];
    }

  unsigned* zt = (unsigned*)&SM[wave][0];
  const uint4* WBq = (const uint4*)WBK;
  f32x4v acc[4][2];
#pragma unroll
  for (int rt = 0; rt < 4; ++rt)
#pragma unroll
    for (int ct = 0; ct < 2; ++ct) { f32x4v z = {0.f, 0.f, 0.f, 0.f}; acc[rt][ct] = z; }

#pragma unroll
  for (int kk = 0; kk < 24; ++kk) {
    f16x2 sp0, sp1;
    if (kk < 8) {
      sp0.x = sp0.y = (_Float16)xs[2 * kk];
      sp1.x = sp1.y = (_Float16)xs[2 * kk + 1];
    } else if (kk < 12) {
      sp0.x = sp0.y = (_Float16)Bv[2 * (kk - 8)];
      sp1.x = sp1.y = (_Float16)Bv[2 * (kk - 8) + 1];
    } else {
      int part = (kk - 12) >> 2, p = (kk - 12) & 3;
      sp0.x = sp0.y = cxv[part][p].x;
      sp1.x = sp1.y = cxv[part][p].y;
    }
    union { uint4 u[4]; f16x2 z[16]; } Z;
#pragma unroll
    for (int t = 0; t < 8; ++t) { Z.z[t] = hp[t] * sp0; Z.z[8 + t] = hp[t] * sp1; }
    uint4* zrow = (uint4*)(zt + lane * ZTW);
    zrow[0] = Z.u[0]; zrow[1] = Z.u[1]; zrow[2] = Z.u[2]; zrow[3] = Z.u[3];
    union { uint4 u; f16x8v v; } af[4];
#pragma unroll
    for (int rt = 0; rt < 4; ++rt)
      af[rt].u = *(const uint4*)(zt + (16 * rt + m) * ZTW + 4 * q);
#pragma unroll
    for (int ct = 0; ct < 2; ++ct) {
      union { uint4 u; f16x8v v; } bf;
      bf.u = WBq[(kk * 2 + ct) * 64 + lane];
#pragma unroll
      for (int rt = 0; rt < 4; ++rt)
        acc[rt][ct] = __builtin_amdgcn_mfma_f32_16x16x32_f16(af[rt].v, bf.v, acc[rt][ct], 0, 0, 0);
    }
  }

  // C -> P[24] via chunked LDS transpose (per-wave in-order; reuses ZT region)
  float P[24];
  float* ctb = &SM[wave][0];
#pragma unroll
  for (int rt = 0; rt < 4; ++rt)
#pragma unroll
    for (int r = 0; r < 4; ++r)
      ctb[(16 * rt + 4 * q + r) * ZTW + m] = acc[rt][0][r];
#pragma unroll
  for (int b = 0; b < 4; ++b) {
    float4 f = *(const float4*)(ctb + lane * ZTW + 4 * b);
    P[4 * b] = f.x; P[4 * b + 1] = f.y; P[4 * b + 2] = f.z; P[4 * b + 3] = f.w;
  }
#pragma unroll
  for (int rt = 0; rt < 4; ++rt)
#pragma unroll
    for (int r = 0; r < 4; ++r)
      ctb[(16 * rt + 4 * q + r) * ZTW + m] = acc[rt][1][r];
#pragma unroll
  for (int b = 0; b < 2; ++b) {
    float4 f = *(const float4*)(ctb + lane * ZTW + 4 * b);
    P[16 + 4 * b] = f.x; P[17 + 4 * b] = f.y; P[18 + 4 * b] = f.z; P[19 + 4 * b] = f.w;
  }

  // sim = q~s . ks + q~v . (y1*s1 + s2)
  float sim = 0.f;
#pragma unroll
  for (int j = 0; j < 8; ++j) sim = fmaf(qts[j], P[j], sim);
  float y1c[3] = {g.y1x, g.y1y, g.y1z};
#pragma unroll
  for (int o = 0; o < 4; ++o)
#pragma unroll
    for (int c = 0; c < 3; ++c)
      sim = fmaf(qtv[3 * o + c], fmaf(y1c[c], P[8 + o], P[12 + 4 * c + o]), sim);
  simb[slot] = sim;
}

// ================= exact per-dst softmax =================
__global__ void k_norm(const int* __restrict__ start, float* __restrict__ simb) {
  int n = blockIdx.x * 256 + threadIdx.x;
  if (n >= N_NODES) return;
  int a = start[n], b = start[n + 1];
  if (a == b) return;
  float m = -3.4e38f;
  for (int j = a; j < b; ++j) m = fmaxf(m, simb[j]);
  float Z = 0.f;
  for (int j = a; j < b; ++j) { float t = __expf(simb[j] - m); simb[j] = t; Z += t; }
  float inv = 1.f / Z;
  for (int j = a; j < b; ++j) simb[j] *= inv;
}

// ======= pass 2: Z-GEMM MFMA — P[64][48] = Z[64][768] x WZV[768][48], chunked CT =======
__global__ void __launch_bounds__(256) k_edge2(
    const float* __restrict__ pos, const float* __restrict__ x,
    const float* __restrict__ Wv1, const unsigned short* __restrict__ WB,
    const int2* __restrict__ sd, const float* __restrict__ ab, float* __restrict__ out) {
  __shared__ __align__(16) unsigned LW1[256];
  __shared__ __align__(16) float SM[4][64 * ZTW];   // per-wave: ZT then CT chunks

  for (int i = threadIdx.x; i < 256; i += 256) {
    int bp = i >> 4, t = i & 15;
    LW1[i] = packh2(Wv1[(2 * bp) * 16 + t] * 0.17677669529663687f,
                    Wv1[(2 * bp + 1) * 16 + t] * 0.17677669529663687f);
  }
  __syncthreads();

  int wave = threadIdx.x >> 6, lane = threadIdx.x & 63;
  int q = lane >> 4, m = lane & 15;
  int slot = blockIdx.x * 256 + threadIdx.x;
  int2 e = sd[slot];
  int s = e.x, d = e.y;

  bool same[6];
#pragma unroll
  for (int k = 0; k < 6; ++k) {
    int dd = __shfl_down(d, 1 << k, 64);
    same[k] = ((lane + (1 << k)) < 64) && (dd == d);
  }
  int dprev = __shfl_up(d, 1, 64);
  bool head = (lane == 0) || (dprev != d);

  f16x2 hp[8]; EdgeGeom g;
  edge_h_pk(pos, s, d, LW1, hp, g);
  float xr[40];
  load_row40(x + 40 * s, xr);
  float xs[16];
#pragma unroll
  for (int i = 0; i < 16; ++i) xs[i] = xr[i];
  float Bv[8];
#pragma unroll
  for (int i = 0; i < 8; ++i)
    Bv[i] = fmaf(xr[16 + 3 * i], g.vhx, fmaf(xr[17 + 3 * i], g.vhy, xr[18 + 3 * i] * g.vhz));
  f16x2 cxv[3][4];
#pragma unroll
  for (int p = 0; p < 4; ++p)
#pragma unroll
    for (int c = 0; c < 3; ++c) {
      cxv[c][p].x = (_Float16)xr[16 + 3 * (2 * p) + c];
      cxv[c][p].y = (_Float16)xr[16 + 3 * (2 * p + 1) + c];
    }
  float a = ab[slot];

  unsigned* zt = (unsigned*)&SM[wave][0];
  const uint4* WBq = (const uint4*)WB;
  f32x4v acc[4][3];
#pragma unroll
  for (int rt = 0; rt < 4; ++rt)
#pragma unroll
    for (int ct = 0; ct < 3; ++ct) { f32x4v z = {0.f, 0.f, 0.f, 0.f}; acc[rt][ct] = z; }

#pragma unroll
  for (int kk = 0; kk < 24; ++kk) {
    f16x2 sp0, sp1;
    if (kk < 8) {
      sp0.x = sp0.y = (_Float16)xs[2 * kk];
      sp1.x = sp1.y = (_Float16)xs[2 * kk + 1];
    } else if (kk < 12) {
      sp0.x = sp0.y = (_Float16)Bv[2 * (kk - 8)];
      sp1.x = sp1.y = (_Float16)Bv[2 * (kk - 8) + 1];
    } else {
      int part = (kk - 12) >> 2, p = (kk - 12) & 3;
      sp0.x = sp0.y = cxv[part][p].x;
      sp1.x = sp1.y = cxv[part][p].y;
    }
    union { uint4 u[4]; f16x2 z[16]; } Z;
#pragma unroll
    for (int t = 0; t < 8; ++t) { Z.z[t] = hp[t] * sp0; Z.z[8 + t] = hp[t] * sp1; }
    uint4* zrow = (uint4*)(zt + lane * ZTW);
    zrow[0] = Z.u[0]; zrow[1] = Z.u[1]; zrow[2] = Z.u[2]; zrow[3] = Z.u[3];
    union { uint4 u; f16x8v v; } af[4];
#pragma unroll
    for (int rt = 0; rt < 4; ++rt)
      af[rt].u = *(const uint4*)(zt + (16 * rt + m) * ZTW + 4 * q);
#pragma unroll
    for (int ct = 0; ct < 3; ++ct) {
      union { uint4 u; f16x8v v; } bf;
      bf.u = WBq[(kk * 3 + ct) * 64 + lane];
#pragma unroll
      for (int rt = 0; rt < 4; ++rt)
        acc[rt][ct] = __builtin_amdgcn_mfma_f32_16x16x32_f16(af[rt].v, bf.v, acc[rt][ct], 0, 0, 0);
    }
  }

  float* ctb = &SM[wave][0];
  float* op = out + 40 * d;

  // chunk 0: out_s cols 0..15 -> scatter
  {
#pragma unroll
    for (int rt = 0; rt < 4; ++rt)
#pragma unroll
      for (int r = 0; r < 4; ++r)
        ctb[(16 * rt + 4 * q + r) * ZTW + m] = acc[rt][0][r];
    float P0[16];
#pragma unroll
    for (int b = 0; b < 4; ++b) {
      float4 f = *(const float4*)(ctb + lane * ZTW + 4 * b);
      P0[4 * b] = f.x; P0[4 * b + 1] = f.y; P0[4 * b + 2] = f.z; P0[4 * b + 3] = f.w;
    }
#pragma unroll
    for (int o = 0; o < 16; ++o) {
      float v = a * P0[o];
#pragma unroll
      for (int k = 0; k < 6; ++k) {
        float ov = __shfl_down(v, 1 << k, 64);
        v += same[k] ? ov : 0.f;
      }
      if (head) atomicAdd(op + o, v);
    }
  }
  // chunks 1,2: s1/s2x and s2y/s2z
  float P1[16], P2[16];
#pragma unroll
  for (int rt = 0; rt < 4; ++rt)
#pragma unroll
    for (int r = 0; r < 4; ++r)
      ctb[(16 * rt + 4 * q + r) * ZTW + m] = acc[rt][1][r];
#pragma unroll
  for (int b = 0; b < 4; ++b) {
    float4 f = *(const float4*)(ctb + lane * ZTW + 4 * b);
    P1[4 * b] = f.x; P1[4 * b + 1] = f.y; P1[4 * b + 2] = f.z; P1[4 * b + 3] = f.w;
  }
#pragma unroll
  for (int rt = 0; rt < 4; ++rt)
#pragma unroll
    for (int r = 0; r < 4; ++r)
      ctb[(16 * rt + 4 * q + r) * ZTW + m] = acc[rt][2][r];
#pragma unroll
  for (int b = 0; b < 4; ++b) {
    float4 f = *(const float4*)(ctb + lane * ZTW + 4 * b);
    P2[4 * b] = f.x; P2[4 * b + 1] = f.y; P2[4 * b + 2] = f.z; P2[4 * b + 3] = f.w;
  }
  // vec outputs: s1=P1[o], s2x=P1[8+o], s2y=P2[o], s2z=P2[8+o]
#pragma unroll
  for (int o = 0; o < 8; ++o) {
    float s1v = P1[o];
    float vc[3];
    vc[0] = a * fmaf(g.y1x, s1v, P1[8 + o]);
    vc[1] = a * fmaf(g.y1y, s1v, P2[o]);
    vc[2] = a * fmaf(g.y1z, s1v, P2[8 + o]);
#pragma unroll
    for (int c = 0; c < 3; ++c) {
      float v = vc[c];
#pragma unroll
      for (int k = 0; k < 6; ++k) {
        float ov = __shfl_down(v, 1 << k, 64);
        v += same[k] ? ov : 0.f;
      }
      if (head) atomicAdd(op + 16 + 3 * o + c, v);
    }
  }
}

extern "C" void kernel_launch(void* const* d_in, const int* in_sizes, int n_in,
                              void* d_out, int out_size, void* d_ws, size_t ws_size,
                              hipStream_t stream) {
  (void)in_sizes; (void)n_in; (void)out_size; (void)ws_size;
  const float* pos  = (const float*)d_in[0];
  const float* x    = (const float*)d_in[1];
  const float* Wq_s = (const float*)d_in[2];
  const float* Wq_v = (const float*)d_in[3];
  const float* Wk1  = (const float*)d_in[4];
  const float* Wk2  = (const float*)d_in[5];
  const float* Wv1  = (const float*)d_in[6];
  const float* Wv2  = (const float*)d_in[7];
  const float* Wss  = (const float*)d_in[8];
  const float* Wvv  = (const float*)d_in[9];
  const int* esrc = (const int*)d_in[10];
  const int* edst = (const int*)d_in[11];
  int*   wsi  = (int*)d_ws;
  float* wsf  = (float*)d_ws;
  float* out  = (float*)d_out;

  int2*  sd    = (int2*)(wsi + OFF_SD);
  float* simb  = wsf + OFF_SIMB;
  int*   cnt   = wsi + OFF_CNT;
  int*   start = wsi + OFF_START;
  int*   cur   = wsi + OFF_CUR;
  unsigned short* WB  = (unsigned short*)(wsf + OFF_WB);
  unsigned short* WBK = (unsigned short*)(wsf + OFF_WBK);

  hipMemsetAsync(cnt, 0, (size_t)N_NODES * sizeof(int), stream);
  hipMemsetAsync(out, 0, (size_t)(N_NODES * 40) * sizeof(float), stream);
  k_prepB<<<144, 256, 0, stream>>>(Wv2, WB);
  k_prepBK<<<96, 256, 0, stream>>>(Wk2, WBK);
  k_hist<<<1000, 256, 0, stream>>>(edst, cnt);
  k_scan<<<1, 1024, 0, stream>>>(cnt, start, cur);
  k_fill<<<1000, 256, 0, stream>>>(esrc, edst, cur, sd);
  k_edge1<<<1000, 256, 0, stream>>>(pos, x, Wq_s, Wq_v, Wk1, Wss, Wvv, WBK, sd, simb);
  k_norm<<<63, 256, 0, stream>>>(start, simb);
  k_edge2<<<1000, 256, 0, stream>>>(pos, x, Wv1, WB, sd, simb, out);
}

// Round 18
// 236.820 us; speedup vs baseline: 1.5871x; 1.0440x over previous
//
#include <hip/hip_runtime.h>
#include <hip/hip_bf16.h>

#define N_NODES 16000
#define N_EDGES 256000

// ---- workspace layout (4-byte units) — total 1006724*4B = 4.03 MB (< r12-exercised 4.29 MB) ----
#define OFF_SD     0          // int2  256000  (src,dst) per CSR slot, sorted by dst
#define OFF_SIMB   512000     // float 256000  raw sim -> normalized a (in place)
#define OFF_CNT    768000     // int   16000   per-dst degree
#define OFF_START  784000     // int   16001   CSR row offsets
#define OFF_CUR    800001     // int   16000   fill cursors
#define OFF_WB     816004     // f16   36864   WZ-V weights, B-frag order (18432 dwords)
#define OFF_WBK    834436     // f16   24576   WZ-K weights, B-frag order (12288 dwords)
#define OFF_QT     846724     // f16   320000  q-tilde per node (20 f16/node; 160000 dwords)

typedef _Float16 f16x2 __attribute__((ext_vector_type(2)));
typedef _Float16 f16x8v __attribute__((ext_vector_type(8)));
typedef float f32x4v __attribute__((ext_vector_type(4)));

__device__ __forceinline__ float fdot2f(f16x2 a, f16x2 b, float c) {
#if __has_builtin(__builtin_amdgcn_fdot2)
  return __builtin_amdgcn_fdot2(a, b, c, false);
#else
  return fmaf((float)a.x, (float)b.x, fmaf((float)a.y, (float)b.y, c));
#endif
}

__device__ __forceinline__ unsigned packh2(float a, float b) {
  union { unsigned u; f16x2 p; } v;
  v.p.x = (_Float16)a; v.p.y = (_Float16)b;
  return v.u;
}

// splat one 16-bit half of a dword across both halves (1 v_perm_b32)
__device__ __forceinline__ unsigned splat_half(unsigned x, unsigned sel) {
#if __has_builtin(__builtin_amdgcn_perm)
  return __builtin_amdgcn_perm(x, x, sel);
#else
  unsigned h = (sel == 0x03020302u) ? (x >> 16) : (x & 0xffffu);
  return h | (h << 16);
#endif
}

__device__ __forceinline__ void load_row40(const float* __restrict__ p, float* xr) {
  const float4* rp = reinterpret_cast<const float4*>(p);
#pragma unroll
  for (int q = 0; q < 10; ++q) {
    float4 f = rp[q];
    xr[4 * q + 0] = f.x; xr[4 * q + 1] = f.y; xr[4 * q + 2] = f.z; xr[4 * q + 3] = f.w;
  }
}

struct EdgeGeom { float vhx, vhy, vhz, y1x, y1y, y1z; };

// geometry + radial basis + h = silu(rad @ W1n), packed as 8 f16 pairs (r11-validated)
__device__ __forceinline__ void edge_h_pk(const float* __restrict__ pos, int s, int d,
                                          const unsigned* W1, f16x2* hp, EdgeGeom& g) {
  float vx = pos[3 * d + 0] - pos[3 * s + 0];
  float vy = pos[3 * d + 1] - pos[3 * s + 1];
  float vz = pos[3 * d + 2] - pos[3 * s + 2];
  float dist = sqrtf(fmaf(vx, vx, fmaf(vy, vy, vz * vz)));
  float dsafe = fmaxf(dist, 1e-6f);
  float rinv = 1.0f / dsafe;
  g.vhx = vx * rinv; g.vhy = vy * rinv; g.vhz = vz * rinv;
  g.y1x = 1.7320508075688772f * g.vhx;
  g.y1y = 1.7320508075688772f * g.vhy;
  g.y1z = 1.7320508075688772f * g.vhz;
  float pre[16];
#pragma unroll
  for (int t = 0; t < 16; ++t) pre[t] = 0.f;
  float sx, cx;
  sincosf(1.2566370614359172f * dsafe, &sx, &cx);
  cx = fminf(1.f, fmaxf(-1.f, cx));
  float twoc = 2.f * cx;
  float sprev = 0.f, scur = sx;
  float rscale = (dist < 2.5f) ? (5.059644256269407f * rinv) : 0.f;
#pragma unroll
  for (int bp = 0; bp < 16; ++bp) {
    float r0 = rscale * scur;
    float sn = fmaf(twoc, scur, -sprev); sprev = scur; scur = sn;
    float r1 = rscale * scur;
    sn = fmaf(twoc, scur, -sprev); sprev = scur; scur = sn;
    union { unsigned u; f16x2 p; } rp; rp.p.x = (_Float16)r0; rp.p.y = (_Float16)r1;
    union { uint4 u[4]; f16x2 p[16]; } w;
    w.u[0] = *(const uint4*)(W1 + bp * 16);
    w.u[1] = *(const uint4*)(W1 + bp * 16 + 4);
    w.u[2] = *(const uint4*)(W1 + bp * 16 + 8);
    w.u[3] = *(const uint4*)(W1 + bp * 16 + 12);
#pragma unroll
    for (int t = 0; t < 16; ++t) pre[t] = fdot2f(rp.p, w.p[t], pre[t]);
  }
#pragma unroll
  for (int tp = 0; tp < 8; ++tp) {
    float h0 = pre[2 * tp]     / (1.f + __expf(-pre[2 * tp]));
    float h1 = pre[2 * tp + 1] / (1.f + __expf(-pre[2 * tp + 1]));
    hp[tp].x = (_Float16)h0; hp[tp].y = (_Float16)h1;
  }
}

// ================= CSR build =================
__global__ void k_hist(const int* __restrict__ edst, int* __restrict__ cnt) {
  int e = blockIdx.x * 256 + threadIdx.x;
  atomicAdd(&cnt[edst[e]], 1);
}

__global__ void __launch_bounds__(1024) k_scan(const int* __restrict__ cnt,
                                               int* __restrict__ start, int* __restrict__ cur) {
  __shared__ int part[1024];
  int t = threadIdx.x;
  int base = t * 16;
  int local[16];
  int sum = 0;
#pragma unroll
  for (int i = 0; i < 16; ++i) {
    int idx = base + i;
    int c = (idx < N_NODES) ? cnt[idx] : 0;
    local[i] = sum; sum += c;
  }
  part[t] = sum;
  __syncthreads();
  for (int off = 1; off < 1024; off <<= 1) {
    int v = (t >= off) ? part[t - off] : 0;
    __syncthreads();
    part[t] += v;
    __syncthreads();
  }
  int prev = (t == 0) ? 0 : part[t - 1];
#pragma unroll
  for (int i = 0; i < 16; ++i) {
    int idx = base + i;
    if (idx < N_NODES) { int st = prev + local[i]; start[idx] = st; cur[idx] = st; }
  }
  if (t == 0) start[N_NODES] = N_EDGES;
}

__global__ void k_fill(const int* __restrict__ esrc, const int* __restrict__ edst,
                       int* __restrict__ cur, int2* __restrict__ sd) {
  int e = blockIdx.x * 256 + threadIdx.x;
  int d = edst[e];
  int slot = atomicAdd(&cur[d], 1);
  sd[slot] = make_int2(esrc[e], d);
}

// ============ prepack WZ-V[768][48] into B-fragment order (r16-validated) ============
__global__ void k_prepB(const float* __restrict__ Wv2, unsigned short* __restrict__ WB) {
  int idx = blockIdx.x * 256 + threadIdx.x;   // 144*256 = 36864
  int j = idx & 7;
  int lane = (idx >> 3) & 63;
  int t3 = idx >> 9;
  int ct = t3 % 3, kk = t3 / 3;
  int q = lane >> 4, m = lane & 15;
  int row = 32 * kk + 8 * q + j;
  int col = 16 * ct + m;
  int t = row & 15;
  float v = 0.f;
  if (row < 256) {
    int i = row >> 4;
    if (col < 16)      v = Wv2[t * 576 + i * 16 + col];
    else if (col < 24) v = Wv2[t * 576 + 384 + i * 8 + (col - 16)];
  } else if (row < 384) {
    int i = (row - 256) >> 4;
    if (col < 16)      v = Wv2[t * 576 + 256 + i * 16 + col];
  } else {
    int part = (row - 384) >> 7;
    int i = ((row - 384) & 127) >> 4;
    int cb = 24 + 8 * part;
    if (col >= cb && col < cb + 8) v = Wv2[t * 576 + 512 + i * 8 + (col - cb)];
  }
  union { unsigned short u; _Float16 h; } cv;
  cv.h = (_Float16)(v * 0.051031036307982884f);
  WB[idx] = cv.u;
}

// ============ prepack WZ-K[768][24->32] into B-fragment order (r17-validated) ============
__global__ void k_prepBK(const float* __restrict__ Wk2, unsigned short* __restrict__ WBK) {
  int idx = blockIdx.x * 256 + threadIdx.x;   // 96*256 = 24576
  int j = idx & 7;
  int lane = (idx >> 3) & 63;
  int t2 = idx >> 9;
  int ct = t2 & 1, kk = t2 >> 1;
  int q = lane >> 4, m = lane & 15;
  int row = 32 * kk + 8 * q + j;
  int col = 16 * ct + m;
  int t = row & 15;
  float v = 0.f;
  if (col < 24) {
    if (row < 256) {
      int i = row >> 4;
      if (col < 8)       v = Wk2[t * 288 + i * 8 + col];
      else if (col < 12) v = Wk2[t * 288 + 192 + i * 4 + (col - 8)];
    } else if (row < 384) {
      int i = (row - 256) >> 4;
      if (col < 8)       v = Wk2[t * 288 + 128 + i * 8 + col];
    } else {
      int c = (row - 384) >> 7;
      int i = ((row - 384) & 127) >> 4;
      int cb = 12 + 4 * c;
      if (col >= cb && col < cb + 4) v = Wk2[t * 288 + 256 + i * 4 + (col - cb)];
    }
  }
  union { unsigned short u; _Float16 h; } cv;
  cv.h = (_Float16)(v * 0.051031036307982884f);
  WBK[idx] = cv.u;
}

// ============ per-node q-tilde (q contracted with Wss/Wvv), f16 store ============
__global__ void __launch_bounds__(128) k_nodeq(
    const float* __restrict__ x,
    const float* __restrict__ Wq_s, const float* __restrict__ Wq_v,
    const float* __restrict__ Wss, const float* __restrict__ Wvv,
    unsigned short* __restrict__ QT) {
  __shared__ float Ls[240];
  for (int i = threadIdx.x; i < 240; i += 128) {
    float v;
    if (i < 128)      v = Wq_s[i] * 0.25f;
    else if (i < 160) v = Wq_v[i - 128] * 0.3535533905932738f;
    else if (i < 224) v = Wss[i - 160] * 0.11180339887498948f;
    else              v = Wvv[i - 224] * 0.06454972243679028f;
    Ls[i] = v;
  }
  __syncthreads();
  int n = blockIdx.x * 128 + threadIdx.x;   // 125*128 = 16000 exact
  float xd[40];
  load_row40(x + 40 * n, xd);
  float qd[8], qvd[12];
#pragma unroll
  for (int o = 0; o < 8; ++o) qd[o] = 0.f;
#pragma unroll
  for (int i = 0; i < 16; ++i)
#pragma unroll
    for (int o = 0; o < 8; ++o) qd[o] = fmaf(xd[i], Ls[8 * i + o], qd[o]);
#pragma unroll
  for (int k = 0; k < 12; ++k) qvd[k] = 0.f;
#pragma unroll
  for (int i = 0; i < 8; ++i)
#pragma unroll
    for (int o = 0; o < 4; ++o)
#pragma unroll
      for (int c = 0; c < 3; ++c)
        qvd[3 * o + c] = fmaf(xd[16 + 3 * i + c], Ls[128 + 4 * i + o], qvd[3 * o + c]);
  float qf[20];
#pragma unroll
  for (int j = 0; j < 8; ++j) {
    float t = 0.f;
#pragma unroll
    for (int i = 0; i < 8; ++i) t = fmaf(qd[i], Ls[160 + 8 * i + j], t);
    qf[j] = t;
  }
#pragma unroll
  for (int o = 0; o < 4; ++o)
#pragma unroll
    for (int c = 0; c < 3; ++c) {
      float t = 0.f;
#pragma unroll
      for (int i = 0; i < 4; ++i) t = fmaf(qvd[3 * i + c], Ls[224 + 4 * i + o], t);
      qf[8 + 3 * o + c] = t;
    }
  uint2* qp = (uint2*)(QT + 20 * n);   // 40B/node, 8B-aligned
#pragma unroll
  for (int b = 0; b < 5; ++b) {
    uint2 st;
    st.x = packh2(qf[4 * b], qf[4 * b + 1]);
    st.y = packh2(qf[4 * b + 2], qf[4 * b + 3]);
    qp[b] = st;
  }
}

// ---- shared per-wave SM row (stride RSTR dwords, 16B-aligned): [0..7] HT (h, 16 f16)
//      [8..31] CF (48 coefs as 24 f16-pair dwords: dword kk = {coef 2kk, coef 2kk+1}) ----
#define RSTR 36

// build coef[48] = {xs(16), Bv(8), xv pairs per component(24)} matching WZ row order
__device__ __forceinline__ void build_coef(const float* xr, const float* Bv, float* coef) {
#pragma unroll
  for (int i = 0; i < 16; ++i) coef[i] = xr[i];
#pragma unroll
  for (int i = 0; i < 8; ++i) coef[16 + i] = Bv[i];
#pragma unroll
  for (int p = 0; p < 4; ++p)
#pragma unroll
    for (int c = 0; c < 3; ++c) {
      coef[24 + 8 * c + 2 * p]     = xr[16 + 6 * p + c];
      coef[24 + 8 * c + 2 * p + 1] = xr[16 + 6 * p + 3 + c];
    }
}

// ======= pass 1: Z-GEMM (CF-splat k-loop) + q~ preload =======
__global__ void __launch_bounds__(256) k_edge1(
    const float* __restrict__ pos, const float* __restrict__ x,
    const float* __restrict__ Wk1, const unsigned short* __restrict__ WBK,
    const unsigned short* __restrict__ QT,
    const int2* __restrict__ sd, float* __restrict__ simb) {
  __shared__ __align__(16) unsigned LW1[256];
  __shared__ __align__(16) unsigned SM[4][64 * RSTR];

  for (int i = threadIdx.x; i < 256; i += 256) {
    int bp = i >> 4, t = i & 15;
    LW1[i] = packh2(Wk1[(2 * bp) * 16 + t] * 0.17677669529663687f,
                    Wk1[(2 * bp + 1) * 16 + t] * 0.17677669529663687f);
  }
  __syncthreads();

  int wave = threadIdx.x >> 6, lane = threadIdx.x & 63;
  int q = lane >> 4, m = lane & 15;
  int q1 = q & 1;
  unsigned seld = (q >> 1) ? 0x03020302u : 0x01000100u;
  int slot = blockIdx.x * 256 + threadIdx.x;
  int2 e = sd[slot];
  int s = e.x, d = e.y;

  f16x2 hp[8]; EdgeGeom g;
  edge_h_pk(pos, s, d, LW1, hp, g);

  // q~ load (f16, 20 halves)
  float qf[20];
  {
    const uint2* qp = (const uint2*)(QT + 20 * d);
#pragma unroll
    for (int b = 0; b < 5; ++b) {
      uint2 u = qp[b];
      union { unsigned d; f16x2 p; } a0, a1;
      a0.d = u.x; a1.d = u.y;
      qf[4 * b] = (float)a0.p.x; qf[4 * b + 1] = (float)a0.p.y;
      qf[4 * b + 2] = (float)a1.p.x; qf[4 * b + 3] = (float)a1.p.y;
    }
  }

  float xr[40];
  load_row40(x + 40 * s, xr);
  float Bv[8];
#pragma unroll
  for (int i = 0; i < 8; ++i)
    Bv[i] = fmaf(xr[16 + 3 * i], g.vhx, fmaf(xr[17 + 3 * i], g.vhy, xr[18 + 3 * i] * g.vhz));
  float coef[48];
  build_coef(xr, Bv, coef);

  unsigned* row = &SM[wave][lane * RSTR];
  {
    union { uint4 u; f16x2 p[4]; } h0, h1;
#pragma unroll
    for (int k = 0; k < 4; ++k) { h0.p[k] = hp[k]; h1.p[k] = hp[4 + k]; }
    *(uint4*)(row) = h0.u;
    *(uint4*)(row + 4) = h1.u;
  }
#pragma unroll
  for (int bt = 0; bt < 6; ++bt) {
    uint4 w;
    w.x = packh2(coef[8 * bt + 0], coef[8 * bt + 1]);
    w.y = packh2(coef[8 * bt + 2], coef[8 * bt + 3]);
    w.z = packh2(coef[8 * bt + 4], coef[8 * bt + 5]);
    w.w = packh2(coef[8 * bt + 6], coef[8 * bt + 7]);
    *(uint4*)(row + 8 + 4 * bt) = w;
  }
  unsigned* wbase = &SM[wave][0];
  union { uint4 u; f16x2 p[4]; } hs[4];
#pragma unroll
  for (int rt = 0; rt < 4; ++rt)
    hs[rt].u = *(const uint4*)(wbase + (16 * rt + m) * RSTR + 4 * q1);

  const uint4* WBq = (const uint4*)WBK;
  f32x4v acc[4][2];
#pragma unroll
  for (int rt = 0; rt < 4; ++rt)
#pragma unroll
    for (int ct = 0; ct < 2; ++ct) { f32x4v z = {0.f, 0.f, 0.f, 0.f}; acc[rt][ct] = z; }

#pragma unroll
  for (int bt = 0; bt < 6; ++bt) {
    union { uint4 u; unsigned d[4]; } cb[4];
#pragma unroll
    for (int rt = 0; rt < 4; ++rt)
      cb[rt].u = *(const uint4*)(wbase + (16 * rt + m) * RSTR + 8 + 4 * bt);
#pragma unroll
    for (int t = 0; t < 4; ++t) {
      int kk = 4 * bt + t;
      union { uint4 u; f16x2 p[4]; f16x8v v; } av[4];
#pragma unroll
      for (int rt = 0; rt < 4; ++rt) {
        union { unsigned d; f16x2 p; } sp;
        sp.d = splat_half(cb[rt].d[t], seld);
#pragma unroll
        for (int w = 0; w < 4; ++w) av[rt].p[w] = hs[rt].p[w] * sp.p;
      }
#pragma unroll
      for (int ct = 0; ct < 2; ++ct) {
        union { uint4 u; f16x8v v; } bf;
        bf.u = WBq[(kk * 2 + ct) * 64 + lane];
#pragma unroll
        for (int rt = 0; rt < 4; ++rt)
          acc[rt][ct] = __builtin_amdgcn_mfma_f32_16x16x32_f16(av[rt].v, bf.v, acc[rt][ct], 0, 0, 0);
      }
    }
  }

  // C -> P via col-major LDS (reuses wave region; per-wave in-order)
  float P[24];
  float* ctb = (float*)wbase;
#pragma unroll
  for (int rt = 0; rt < 4; ++rt)
#pragma unroll
    for (int r = 0; r < 4; ++r)
      ctb[m * 65 + 16 * rt + 4 * q + r] = acc[rt][0][r];
#pragma unroll
  for (int o = 0; o < 16; ++o) P[o] = ctb[o * 65 + lane];
#pragma unroll
  for (int rt = 0; rt < 4; ++rt)
#pragma unroll
    for (int r = 0; r < 4; ++r)
      ctb[m * 65 + 16 * rt + 4 * q + r] = acc[rt][1][r];
#pragma unroll
  for (int o = 0; o < 8; ++o) P[16 + o] = ctb[o * 65 + lane];

  float sim = 0.f;
#pragma unroll
  for (int j = 0; j < 8; ++j) sim = fmaf(qf[j], P[j], sim);
  float y1c[3] = {g.y1x, g.y1y, g.y1z};
#pragma unroll
  for (int o = 0; o < 4; ++o)
#pragma unroll
    for (int c = 0; c < 3; ++c)
      sim = fmaf(qf[8 + 3 * o + c], fmaf(y1c[c], P[8 + o], P[12 + 4 * c + o]), sim);
  simb[slot] = sim;
}

// ================= exact per-dst softmax =================
__global__ void k_norm(const int* __restrict__ start, float* __restrict__ simb) {
  int n = blockIdx.x * 256 + threadIdx.x;
  if (n >= N_NODES) return;
  int a = start[n], b = start[n + 1];
  if (a == b) return;
  float m = -3.4e38f;
  for (int j = a; j < b; ++j) m = fmaxf(m, simb[j]);
  float Z = 0.f;
  for (int j = a; j < b; ++j) { float t = __expf(simb[j] - m); simb[j] = t; Z += t; }
  float inv = 1.f / Z;
  for (int j = a; j < b; ++j) simb[j] *= inv;
}

// ======= pass 2: Z-GEMM (CF-splat k-loop) + segmented scatter =======
__global__ void __launch_bounds__(256) k_edge2(
    const float* __restrict__ pos, const float* __restrict__ x,
    const float* __restrict__ Wv1, const unsigned short* __restrict__ WB,
    const int2* __restrict__ sd, const float* __restrict__ ab, float* __restrict__ out) {
  __shared__ __align__(16) unsigned LW1[256];
  __shared__ __align__(16) unsigned SM[4][64 * RSTR];

  for (int i = threadIdx.x; i < 256; i += 256) {
    int bp = i >> 4, t = i & 15;
    LW1[i] = packh2(Wv1[(2 * bp) * 16 + t] * 0.17677669529663687f,
                    Wv1[(2 * bp + 1) * 16 + t] * 0.17677669529663687f);
  }
  __syncthreads();

  int wave = threadIdx.x >> 6, lane = threadIdx.x & 63;
  int q = lane >> 4, m = lane & 15;
  int q1 = q & 1;
  unsigned seld = (q >> 1) ? 0x03020302u : 0x01000100u;
  int slot = blockIdx.x * 256 + threadIdx.x;
  int2 e = sd[slot];
  int s = e.x, d = e.y;

  bool same[6];
#pragma unroll
  for (int k = 0; k < 6; ++k) {
    int dd = __shfl_down(d, 1 << k, 64);
    same[k] = ((lane + (1 << k)) < 64) && (dd == d);
  }
  int dprev = __shfl_up(d, 1, 64);
  bool head = (lane == 0) || (dprev != d);

  f16x2 hp[8]; EdgeGeom g;
  edge_h_pk(pos, s, d, LW1, hp, g);
  float xr[40];
  load_row40(x + 40 * s, xr);
  float Bv[8];
#pragma unroll
  for (int i = 0; i < 8; ++i)
    Bv[i] = fmaf(xr[16 + 3 * i], g.vhx, fmaf(xr[17 + 3 * i], g.vhy, xr[18 + 3 * i] * g.vhz));
  float coef[48];
  build_coef(xr, Bv, coef);
  float a = ab[slot];

  unsigned* row = &SM[wave][lane * RSTR];
  {
    union { uint4 u; f16x2 p[4]; } h0, h1;
#pragma unroll
    for (int k = 0; k < 4; ++k) { h0.p[k] = hp[k]; h1.p[k] = hp[4 + k]; }
    *(uint4*)(row) = h0.u;
    *(uint4*)(row + 4) = h1.u;
  }
#pragma unroll
  for (int bt = 0; bt < 6; ++bt) {
    uint4 w;
    w.x = packh2(coef[8 * bt + 0], coef[8 * bt + 1]);
    w.y = packh2(coef[8 * bt + 2], coef[8 * bt + 3]);
    w.z = packh2(coef[8 * bt + 4], coef[8 * bt + 5]);
    w.w = packh2(coef[8 * bt + 6], coef[8 * bt + 7]);
    *(uint4*)(row + 8 + 4 * bt) = w;
  }
  unsigned* wbase = &SM[wave][0];
  union { uint4 u; f16x2 p[4]; } hs[4];
#pragma unroll
  for (int rt = 0; rt < 4; ++rt)
    hs[rt].u = *(const uint4*)(wbase + (16 * rt + m) * RSTR + 4 * q1);

  const uint4* WBq = (const uint4*)WB;
  f32x4v acc[4][3];
#pragma unroll
  for (int rt = 0; rt < 4; ++rt)
#pragma unroll
    for (int ct = 0; ct < 3; ++ct) { f32x4v z = {0.f, 0.f, 0.f, 0.f}; acc[rt][ct] = z; }

#pragma unroll
  for (int bt = 0; bt < 6; ++bt) {
    union { uint4 u; unsigned d[4]; } cb[4];
#pragma unroll
    for (int rt = 0; rt < 4; ++rt)
      cb[rt].u = *(const uint4*)(wbase + (16 * rt + m) * RSTR + 8 + 4 * bt);
#pragma unroll
    for (int t = 0; t < 4; ++t) {
      int kk = 4 * bt + t;
      union { uint4 u; f16x2 p[4]; f16x8v v; } av[4];
#pragma unroll
      for (int rt = 0; rt < 4; ++rt) {
        union { unsigned d; f16x2 p; } sp;
        sp.d = splat_half(cb[rt].d[t], seld);
#pragma unroll
        for (int w = 0; w < 4; ++w) av[rt].p[w] = hs[rt].p[w] * sp.p;
      }
#pragma unroll
      for (int ct = 0; ct < 3; ++ct) {
        union { uint4 u; f16x8v v; } bf;
        bf.u = WBq[(kk * 3 + ct) * 64 + lane];
#pragma unroll
        for (int rt = 0; rt < 4; ++rt)
          acc[rt][ct] = __builtin_amdgcn_mfma_f32_16x16x32_f16(av[rt].v, bf.v, acc[rt][ct], 0, 0, 0);
      }
    }
  }

  float* ctb = (float*)wbase;
  float* op = out + 40 * d;

  // chunk 0: out_s cols 0..15
  {
#pragma unroll
    for (int rt = 0; rt < 4; ++rt)
#pragma unroll
      for (int r = 0; r < 4; ++r)
        ctb[m * 65 + 16 * rt + 4 * q + r] = acc[rt][0][r];
    float P0[16];
#pragma unroll
    for (int o = 0; o < 16; ++o) P0[o] = ctb[o * 65 + lane];
#pragma unroll
    for (int o = 0; o < 16; ++o) {
      float v = a * P0[o];
#pragma unroll
      for (int k = 0; k < 6; ++k) {
        float ov = __shfl_down(v, 1 << k, 64);
        v += same[k] ? ov : 0.f;
      }
      if (head) atomicAdd(op + o, v);
    }
  }
  // chunks 1,2
  float P1[16], P2[16];
#pragma unroll
  for (int rt = 0; rt < 4; ++rt)
#pragma unroll
    for (int r = 0; r < 4; ++r)
      ctb[m * 65 + 16 * rt + 4 * q + r] = acc[rt][1][r];
#pragma unroll
  for (int o = 0; o < 16; ++o) P1[o] = ctb[o * 65 + lane];
#pragma unroll
  for (int rt = 0; rt < 4; ++rt)
#pragma unroll
    for (int r = 0; r < 4; ++r)
      ctb[m * 65 + 16 * rt + 4 * q + r] = acc[rt][2][r];
#pragma unroll
  for (int o = 0; o < 16; ++o) P2[o] = ctb[o * 65 + lane];
#pragma unroll
  for (int o = 0; o < 8; ++o) {
    float s1v = P1[o];
    float vc[3];
    vc[0] = a * fmaf(g.y1x, s1v, P1[8 + o]);
    vc[1] = a * fmaf(g.y1y, s1v, P2[o]);
    vc[2] = a * fmaf(g.y1z, s1v, P2[8 + o]);
#pragma unroll
    for (int c = 0; c < 3; ++c) {
      float v = vc[c];
#pragma unroll
      for (int k = 0; k < 6; ++k) {
        float ov = __shfl_down(v, 1 << k, 64);
        v += same[k] ? ov : 0.f;
      }
      if (head) atomicAdd(op + 16 + 3 * o + c, v);
    }
  }
}

extern "C" void kernel_launch(void* const* d_in, const int* in_sizes, int n_in,
                              void* d_out, int out_size, void* d_ws, size_t ws_size,
                              hipStream_t stream) {
  (void)in_sizes; (void)n_in; (void)out_size; (void)ws_size;
  const float* pos  = (const float*)d_in[0];
  const float* x    = (const float*)d_in[1];
  const float* Wq_s = (const float*)d_in[2];
  const float* Wq_v = (const float*)d_in[3];
  const float* Wk1  = (const float*)d_in[4];
  const float* Wk2  = (const float*)d_in[5];
  const float* Wv1  = (const float*)d_in[6];
  const float* Wv2  = (const float*)d_in[7];
  const float* Wss  = (const float*)d_in[8];
  const float* Wvv  = (const float*)d_in[9];
  const int* esrc = (const int*)d_in[10];
  const int* edst = (const int*)d_in[11];
  int*   wsi  = (int*)d_ws;
  float* wsf  = (float*)d_ws;
  float* out  = (float*)d_out;

  int2*  sd    = (int2*)(wsi + OFF_SD);
  float* simb  = wsf + OFF_SIMB;
  int*   cnt   = wsi + OFF_CNT;
  int*   start = wsi + OFF_START;
  int*   cur   = wsi + OFF_CUR;
  unsigned short* WB  = (unsigned short*)(wsf + OFF_WB);
  unsigned short* WBK = (unsigned short*)(wsf + OFF_WBK);
  unsigned short* QT  = (unsigned short*)(wsf + OFF_QT);

  hipMemsetAsync(cnt, 0, (size_t)N_NODES * sizeof(int), stream);
  hipMemsetAsync(out, 0, (size_t)(N_NODES * 40) * sizeof(float), stream);
  k_prepB<<<144, 256, 0, stream>>>(Wv2, WB);
  k_prepBK<<<96, 256, 0, stream>>>(Wk2, WBK);
  k_nodeq<<<125, 128, 0, stream>>>(x, Wq_s, Wq_v, Wss, Wvv, QT);
  k_hist<<<1000, 256, 0, stream>>>(edst, cnt);
  k_scan<<<1, 1024, 0, stream>>>(cnt, start, cur);
  k_fill<<<1000, 256, 0, stream>>>(esrc, edst, cur, sd);
  k_edge1<<<1000, 256, 0, stream>>>(pos, x, Wk1, WBK, QT, sd, simb);
  k_norm<<<63, 256, 0, stream>>>(start, simb);
  k_edge2<<<1000, 256, 0, stream>>>(pos, x, Wv1, WB, sd, simb, out);
}